// Round 11
// baseline (368.764 us; speedup 1.0000x reference)
//
#include <hip/hip_runtime.h>

typedef __bf16 bf16;
typedef __attribute__((ext_vector_type(8))) __bf16 bf16x8;
typedef __attribute__((ext_vector_type(4))) __bf16 bf16x4;
typedef __attribute__((ext_vector_type(4))) float f32x4;

#define MFMA16(a,b,c) __builtin_amdgcn_mfma_f32_16x16x32_bf16((a),(b),(c),0,0,0)

#define CC 2
#define BB 128
#define EPAD 4096           // 64 dst * 64 padded src-rows
#define EDGE_CNT_INV (1.0f/516096.0f)   // C*4032*64
#define NODE_CNT_INV (1.0f/8192.0f)     // C*64*64
#define LNEPS 1e-5f

// bias pack offsets (elements) in bc[]
#define BC_EB0F 0
#define BC_EB0R 128
#define BC_EB1  384
#define BC_EB2  768
#define BC_NB0  1152
#define BC_NB1  1536
#define BC_NB2  1920
#define BC_TOT  2304

static __device__ __forceinline__ f32x4 zf4(){ f32x4 z = {0.f,0.f,0.f,0.f}; return z; }

// ---- dtype hedge (used ONLY in k_prep) ----
static __device__ __forceinline__ bool detectBf16(const void* p){
  const unsigned short* u = (const unsigned short*)p;
  int ok = 0;
#pragma unroll
  for (int i = 0; i < 64; ++i){
    unsigned v = u[i];
    unsigned e = (v >> 7) & 0xFFu;
    ok += (int)(((e >= 100u) && (e <= 150u)) || (v == 0u));
  }
  return ok >= 58;
}

static __device__ __forceinline__ float ldS(const void* p, long i, bool b16){
  return b16 ? (float)(((const bf16*)p)[i]) : ((const float*)p)[i];
}
static __device__ __forceinline__ void ld8(const void* p, long i, bool b16, float* o){
  if (b16){
    bf16x8 v = *(const bf16x8*)((const bf16*)p + i);
#pragma unroll
    for (int u=0;u<8;u++) o[u] = (float)v[u];
  } else {
    const float* f = (const float*)p + i;
    float4 a = *(const float4*)f; float4 b = *(const float4*)(f+4);
    o[0]=a.x;o[1]=a.y;o[2]=a.z;o[3]=a.w;o[4]=b.x;o[5]=b.y;o[6]=b.z;o[7]=b.w;
  }
}

// ---- LDS swizzles ----
static __device__ __forceinline__ unsigned sw128(unsigned row, unsigned cb){
  return row*128u + (cb ^ ((row&7u)<<4));
}
static __device__ __forceinline__ unsigned sw256(unsigned row, unsigned cb){
  return row*256u + (cb ^ ((row&7u)<<4));
}

static __device__ __forceinline__ void stage64(char* lds, const bf16* src, int tid){
#pragma unroll
  for (int q=0;q<2;q++){
    int idx = tid + q*256;
    int r = idx>>3; unsigned cb = (unsigned)((idx&7)*16);
    *(int4*)(lds + sw128((unsigned)r, cb)) = *(const int4*)((const char*)src + r*128 + cb);
  }
}
static __device__ __forceinline__ void stage128(char* lds, const bf16* src, int tid){
#pragma unroll
  for (int q=0;q<4;q++){
    int idx = tid + q*256;
    int r = idx>>4; unsigned cb = (unsigned)((idx&15)*16);
    *(int4*)(lds + sw256((unsigned)r, cb)) = *(const int4*)((const char*)src + r*256 + cb);
  }
}

static __device__ __forceinline__ bf16x8 frd64(const char* p, int row, int ks, int lane){
  return *(const bf16x8*)(p + sw128((unsigned)row, (unsigned)(ks*64 + ((lane>>4)<<4))));
}
static __device__ __forceinline__ bf16x8 frd256(const char* p, int row, int ks, int lane){
  return *(const bf16x8*)(p + sw256((unsigned)row, (unsigned)(ks*64 + ((lane>>4)<<4))));
}

// GEMM with A-fragments in registers; B from LDS
template<int NMT>
static __device__ __forceinline__ void gemmR(const bf16x8 (&af)[4][2], const char* hlds, int lane, f32x4 (*acc)[NMT]){
  int m15 = lane & 15;
#pragma unroll
  for (int mt=0;mt<NMT;mt++){
    bf16x8 b0 = frd64(hlds, mt*16+m15, 0, lane);
    bf16x8 b1 = frd64(hlds, mt*16+m15, 1, lane);
#pragma unroll
    for (int nt=0;nt<4;nt++){
      acc[nt][mt] = MFMA16(af[nt][0], b0, acc[nt][mt]);
      acc[nt][mt] = MFMA16(af[nt][1], b1, acc[nt][mt]);
    }
  }
}
// GEMM with A from LDS
template<int NMT>
static __device__ __forceinline__ void gemm64(const char* wlds, const char* hlds, int lane, f32x4 (*acc)[NMT]){
  int m15 = lane & 15;
  bf16x8 af[4][2];
#pragma unroll
  for (int nt=0;nt<4;nt++){
    af[nt][0] = frd64(wlds, nt*16+m15, 0, lane);
    af[nt][1] = frd64(wlds, nt*16+m15, 1, lane);
  }
#pragma unroll
  for (int mt=0;mt<NMT;mt++){
    bf16x8 b0 = frd64(hlds, mt*16+m15, 0, lane);
    bf16x8 b1 = frd64(hlds, mt*16+m15, 1, lane);
#pragma unroll
    for (int nt=0;nt<4;nt++){
      acc[nt][mt] = MFMA16(af[nt][0], b0, acc[nt][mt]);
      acc[nt][mt] = MFMA16(af[nt][1], b1, acc[nt][mt]);
    }
  }
}

template<int NMT>
static __device__ __forceinline__ void accZero(f32x4 (*acc)[NMT]){
#pragma unroll
  for (int a=0;a<4;a++){ for (int m=0;m<NMT;m++) acc[a][m] = zf4(); }
}
template<int NMT>
static __device__ __forceinline__ void accBias(const bf16* bias, int lane, f32x4 (*acc)[NMT]){
  int hi = lane>>4;
#pragma unroll
  for (int nt=0;nt<4;nt++){
    f32x4 bv;
#pragma unroll
    for (int r=0;r<4;r++) bv[r] = (float)bias[nt*16 + hi*4 + r];
#pragma unroll
    for (int mt=0;mt<NMT;mt++) acc[nt][mt] = bv;
  }
}
template<int NMT>
static __device__ __forceinline__ void epiRelu(char* hlds, int lane, f32x4 (*acc)[NMT]){
  int hi = lane>>4, m15 = lane&15;
#pragma unroll
  for (int nt=0;nt<4;nt++){
#pragma unroll
    for (int mt=0;mt<NMT;mt++){
      f32x4 v = acc[nt][mt];
      bf16x4 o;
#pragma unroll
      for (int r=0;r<4;r++){
        float t = v[r];
        t = t > 0.f ? t : 0.f;
        o[r] = (bf16)t;
      }
      *(bf16x4*)(hlds + sw128((unsigned)(mt*16+m15), (unsigned)(nt*32 + hi*8))) = o;
    }
  }
}

// =================== PREP ===================
__global__ void k_prep(const void* nodes,
    const void* eW0f, const void* eW0r, const void* eW1, const void* eW2,
    const void* nW0, const void* nW1, const void* nW2,
    const void* ln_ew, const void* ln_eb, const void* ln_nw, const void* ln_nb,
    const void* eb0f, const void* eb0r, const void* eb1, const void* eb2,
    const void* nb0, const void* nb1, const void* nb2,
    bf16* WTpd, bf16* WTps, bf16* WTe0e, bf16* WTe1, bf16* WTe2,
    bf16* WTn0, bf16* WTn1, bf16* WTn2,
    bf16* lnwP, bf16* lnbP,
    bf16* xn0, bf16* lnnW, bf16* lnnB, bf16* bc, int* flag)
{
  bool b16 = detectBf16(nodes);
  int tid = threadIdx.x, blk = blockIdx.x;
  if (blk < 256){
    int t = blk>>7, c = (blk>>6)&1, j = blk&63;
    int k = tid>>2, part = tid&3;
    long dofs = (((long)(t*CC + c))*EPAD + j*64 + k)*64 + part*16;
    if (k < 63){
      int i = k + (k>=j ? 1 : 0);
      int eref = i*63 + j - (j>i ? 1 : 0);
      long sofs = (((long)(t*CC + c))*4032 + eref)*64 + part*16;
      float o[8]; bf16x8 v;
      ld8(ln_ew, sofs,   b16, o); for (int u=0;u<8;u++) v[u]=(bf16)o[u]; *(bf16x8*)(lnwP+dofs)   = v;
      ld8(ln_ew, sofs+8, b16, o); for (int u=0;u<8;u++) v[u]=(bf16)o[u]; *(bf16x8*)(lnwP+dofs+8) = v;
      ld8(ln_eb, sofs,   b16, o); for (int u=0;u<8;u++) v[u]=(bf16)o[u]; *(bf16x8*)(lnbP+dofs)   = v;
      ld8(ln_eb, sofs+8, b16, o); for (int u=0;u<8;u++) v[u]=(bf16)o[u]; *(bf16x8*)(lnbP+dofs+8) = v;
    } else {
      bf16x8 z; for (int u=0;u<8;u++) z[u]=(bf16)0.f;
      *(bf16x8*)(lnwP+dofs)=z; *(bf16x8*)(lnwP+dofs+8)=z;
      *(bf16x8*)(lnbP+dofs)=z; *(bf16x8*)(lnbP+dofs+8)=z;
    }
    return;
  }
  int job = blk - 256;
  if (job < 46){
    const void* src = nullptr; bf16* dst = nullptr; int K = 64; long so = 0;
    if (job < 6){        int t=job>>1, c=job&1; dst = WTpd + (long)(t*CC+c)*4096;
      if (t==0){ src=eW0f; so=(long)c*128*64; } else { src=eW0r; so=((long)(t-1)*CC+c)*192*64; } }
    else if (job < 12){  int q=job-6; int t=q>>1,c=q&1; dst = WTps + (long)(t*CC+c)*4096;
      if (t==0){ src=eW0f; so=(long)c*128*64 + 64*64; } else { src=eW0r; so=((long)(t-1)*CC+c)*192*64 + 64*64; } }
    else if (job < 16){  int q=job-12; int t=q>>1,c=q&1; dst=WTe0e + (long)(t*CC+c)*4096; src=eW0r; so=((long)t*CC+c)*192*64 + 128*64; }
    else if (job < 22){  int q=job-16; int t=q>>1,c=q&1; dst=WTe1 + (long)(t*CC+c)*4096; src=eW1; so=((long)t*CC+c)*4096; }
    else if (job < 28){  int q=job-22; int t=q>>1,c=q&1; dst=WTe2 + (long)(t*CC+c)*4096; src=eW2; so=((long)t*CC+c)*4096; }
    else if (job < 34){  int q=job-28; int t=q>>1,c=q&1; dst=WTn0 + (long)(t*CC+c)*8192; src=nW0; so=((long)t*CC+c)*128*64; K=128; }
    else if (job < 40){  int q=job-34; int t=q>>1,c=q&1; dst=WTn1 + (long)(t*CC+c)*4096; src=nW1; so=((long)t*CC+c)*4096; }
    else              {  int q=job-40; int t=q>>1,c=q&1; dst=WTn2 + (long)(t*CC+c)*4096; src=nW2; so=((long)t*CC+c)*4096; }
    for (int idx = tid; idx < K*64; idx += 256){
      int n = idx & 63, k = idx >> 6;
      dst[(long)n*K + k] = (bf16)ldS(src, so + (long)k*64 + n, b16);
    }
  } else if (job < 110){
    long base = (long)(job-46)*8192;
#pragma unroll
    for (int k=0;k<4;k++){
      long o = base + k*2048 + tid*8;
      float t[8]; ld8(nodes, o, b16, t);
      bf16x8 v;
#pragma unroll
      for (int u=0;u<8;u++) v[u]=(bf16)t[u];
      *(bf16x8*)(xn0 + o) = v;
    }
  } else if (job < 122){
    int q = job-110;
    const void* src = (q<6) ? ln_nw : ln_nb;
    bf16* dst = (q<6) ? lnnW : lnnB;
    long base = (long)(q%6)*4096;
#pragma unroll
    for (int k=0;k<2;k++){
      long o = base + k*2048 + tid*8;
      float t[8]; ld8(src, o, b16, t);
      bf16x8 v;
#pragma unroll
      for (int u=0;u<8;u++) v[u]=(bf16)t[u];
      *(bf16x8*)(dst + o) = v;
    }
  } else {
    for (int idx = tid; idx < BC_TOT; idx += 256){
      float v;
      if      (idx < BC_EB0R) v = ldS(eb0f, idx - BC_EB0F, b16);
      else if (idx < BC_EB1 ) v = ldS(eb0r, idx - BC_EB0R, b16);
      else if (idx < BC_EB2 ) v = ldS(eb1,  idx - BC_EB1,  b16);
      else if (idx < BC_NB0 ) v = ldS(eb2,  idx - BC_EB2,  b16);
      else if (idx < BC_NB1 ) v = ldS(nb0,  idx - BC_NB0,  b16);
      else if (idx < BC_NB2 ) v = ldS(nb1,  idx - BC_NB1,  b16);
      else                    v = ldS(nb2,  idx - BC_NB2,  b16);
      bc[idx] = (bf16)v;
    }
    if (tid == 0) flag[0] = b16 ? 1 : 0;
  }
}

// =================== P0: Xd/Xs (bf16) = nodes@W0d + b0 / nodes@W0s ===================
__global__ __launch_bounds__(256,2) void k_p0(const bf16* xn0,
    const bf16* WTpd, const bf16* WTps, const bf16* bc, bf16* Xd, bf16* Xs)
{
  int tid=threadIdx.x, lane=tid&63, w=tid>>6;
  int b = blockIdx.x;
  extern __shared__ char sm[];
  char* xn = sm;
  char* Wp = sm + 8192;
  stage64(xn, xn0 + (long)b*4096, tid);
  stage64(Wp,         WTpd + 0,    tid);
  stage64(Wp + 8192,  WTps + 0,    tid);
  stage64(Wp + 16384, WTpd + 4096, tid);
  stage64(Wp + 24576, WTps + 4096, tid);
  __syncthreads();
  int c = w>>1, p = w&1;
  f32x4 acc[4][4];
  if (p==0) accBias<4>(bc + BC_EB0F + c*64, lane, acc);
  else accZero<4>(acc);
  gemm64<4>(Wp + (c*2+p)*8192, xn, lane, acc);
  int hi=lane>>4, m15=lane&15;
  bf16* dst = (p==0 ? Xd : Xs) + ((long)c*BB + b)*64*64;
#pragma unroll
  for (int nt=0;nt<4;nt++){
#pragma unroll
    for (int mt=0;mt<4;mt++){
      f32x4 v = acc[nt][mt];
      bf16x4 o = {(bf16)v[0],(bf16)v[1],(bf16)v[2],(bf16)v[3]};
      *(bf16x4*)(dst + (long)(mt*16+m15)*64 + nt*16+hi*4) = o;
    }
  }
}

// =================== EDGE kernel ===================
// LDS = Wl1 8K + Wl2 8K + 4x8K hb = 48KB -> 3 blocks/CU (12 waves). Xd/Xs read
// directly from global as bf16 (L2-hot). Wl0 as register A-fragments loaded after
// normalize (sequential liveness: pe/lwv/lbv 96 -> af0+xsv 48 + acc 64; peak ~112).
template<int T>
__global__ __launch_bounds__(256,3) void k_edge(
    bf16* edges, const bf16* Xd, const bf16* Xs, float* agg, float* eS,
    const float2* eMR,
    const bf16* WTe0e, const bf16* WTe1, const bf16* WTe2,
    const bf16* lnwP, const bf16* lnbP, const bf16* bc)
{
  int tid=threadIdx.x, lane=tid&63, w=tid>>6;
  int jt = blockIdx.x, b = blockIdx.y, c = blockIdx.z;
  int j = jt*4 + w;
  extern __shared__ char sm[];
  char* Wl1 = sm;
  char* Wl2 = sm + 8192;
  char* hb  = sm + 16384 + w*8192;     // per-wave [64][64] bf16

  long cb = (long)c*BB + b;
  int hi = lane>>4, m15 = lane&15;
  int mrow = lane>>3;
  unsigned cbyte = (unsigned)((lane&7)*16);
  int cbk = (lane&7)*8;

  bf16* erow = edges + (cb*EPAD + (long)j*64)*64;
  const bf16* xdrow = Xd + (cb*64 + j)*64;
  const bf16* xsbase = Xs + cb*64*64;

  // hoisted per-(T,b) LN stats
  float mu = 0.f, rs = 0.f;
  if (T>0){ float2 mr = eMR[(T-1)*BB + b]; mu = mr.x; rs = mr.y; }

  // prefetch this chain's input streams (registers freed at normalize)
  bf16x8 pe[8], lwv[8], lbv[8];
  if (T>0){
    const char* lw = (const char*)(lnwP + (((long)(T-1)*CC+c)*EPAD + (long)j*64)*64);
    const char* lb = (const char*)(lnbP + (((long)(T-1)*CC+c)*EPAD + (long)j*64)*64);
#pragma unroll
    for (int it=0; it<8; it++){
      pe[it]  = *(const bf16x8*)((const char*)erow + (mrow+it*8)*128 + cbyte);
      lwv[it] = *(const bf16x8*)(lw + (mrow+it*8)*128 + cbyte);
      lbv[it] = *(const bf16x8*)(lb + (mrow+it*8)*128 + cbyte);
    }
  }
  // T==0: Xd row prefetch (bf16)
  bf16x8 xd8v;
  if (T==0) xd8v = *(const bf16x8*)(xdrow + cbk);

  // stage weights to LDS (block-invariant)
  stage64(Wl1, WTe1 + (long)(T*CC+c)*4096, tid);
  stage64(Wl2, WTe2 + (long)(T*CC+c)*4096, tid);
  __syncthreads();

  f32x4 acc[4][4];

  if (T==0){
    float xd8[8];
#pragma unroll
    for (int u=0;u<8;u++) xd8[u] = (float)xd8v[u];
#pragma unroll
    for (int it=0; it<8; it++){
      int m = mrow + it*8;
      int i = m + (m>=j ? 1 : 0); if (i>63) i = 63;
      bf16x8 y8 = *(const bf16x8*)(xsbase + (long)i*64 + cbk);
      bf16x8 o;
#pragma unroll
      for (int u=0;u<8;u++){
        float tt = xd8[u] + (float)y8[u];
        tt = tt > 0.f ? tt : 0.f;
        o[u] = (bf16)tt;
      }
      *(bf16x8*)(hb + sw128((unsigned)m, (unsigned)(cbk*2))) = o;
    }
    accBias<4>(bc + BC_EB1 + (T*CC+c)*64, lane, acc);
    gemm64<4>(Wl1, hb, lane, acc);
    epiRelu<4>(hb, lane, acc);
    accBias<4>(bc + BC_EB2 + (T*CC+c)*64, lane, acc);
    gemm64<4>(Wl2, hb, lane, acc);
  } else {
    // normalize prefetched edges -> hb (frees pe/lwv/lbv)
#pragma unroll
    for (int it=0; it<8; it++){
      int m = mrow + it*8;
      bf16x8 e = pe[it];
      bf16x8 o;
#pragma unroll
      for (int u=0;u<8;u++){
        float tt = ((float)e[u] - mu) * rs;
        tt = tt * (float)lwv[it][u] + (float)lbv[it][u];
        o[u] = (bf16)tt;
      }
      *(bf16x8*)(hb + sw128((unsigned)m, cbyte)) = o;
    }
    // issue W0e A-fragments + epilogue0 operands (consumed after/during GEMM0)
    bf16x8 af0[4][2];
    {
      const bf16* w0 = WTe0e + (long)((T-1)*CC+c)*4096;
#pragma unroll
      for (int nt=0;nt<4;nt++){
#pragma unroll
        for (int ks=0;ks<2;ks++)
          af0[nt][ks] = *(const bf16x8*)(w0 + (nt*16+m15)*64 + ks*32 + hi*8);
      }
    }
    bf16x4 xdv[4], xsv[4][4];
#pragma unroll
    for (int nt=0;nt<4;nt++) xdv[nt] = *(const bf16x4*)(xdrow + nt*16 + hi*4);
#pragma unroll
    for (int mt=0;mt<4;mt++){
      int m = mt*16 + m15;
      int i = m + (m>=j ? 1 : 0); if (i>63) i=63;
#pragma unroll
      for (int nt=0;nt<4;nt++)
        xsv[mt][nt] = *(const bf16x4*)(xsbase + (long)i*64 + nt*16 + hi*4);
    }
    accZero<4>(acc);
    gemmR<4>(af0, hb, lane, acc);
    // epilogue0: + Xd'[j] + Xs[i(m)], relu -> h0
#pragma unroll
    for (int mt=0;mt<4;mt++){
      int m = mt*16 + m15;
#pragma unroll
      for (int nt=0;nt<4;nt++){
        f32x4 v = acc[nt][mt];
        float t0 = v[0] + (float)xdv[nt][0] + (float)xsv[mt][nt][0];
        float t1 = v[1] + (float)xdv[nt][1] + (float)xsv[mt][nt][1];
        float t2 = v[2] + (float)xdv[nt][2] + (float)xsv[mt][nt][2];
        float t3 = v[3] + (float)xdv[nt][3] + (float)xsv[mt][nt][3];
        bf16x4 o;
        o[0] = (bf16)(t0>0.f?t0:0.f); o[1] = (bf16)(t1>0.f?t1:0.f);
        o[2] = (bf16)(t2>0.f?t2:0.f); o[3] = (bf16)(t3>0.f?t3:0.f);
        *(bf16x4*)(hb + sw128((unsigned)m, (unsigned)(nt*32+hi*8))) = o;
      }
    }
    accBias<4>(bc + BC_EB1 + (T*CC+c)*64, lane, acc);
    gemm64<4>(Wl1, hb, lane, acc);
    epiRelu<4>(hb, lane, acc);
    accBias<4>(bc + BC_EB2 + (T*CC+c)*64, lane, acc);
    gemm64<4>(Wl2, hb, lane, acc);
  }

  // ---- final epilogue ----
  if (m15 == 15){
#pragma unroll
    for (int nt=0;nt<4;nt++) acc[nt][3] = zf4();
  }
  if (T < 2){
    float s1=0.f, s2=0.f;
#pragma unroll
    for (int nt=0;nt<4;nt++){ for (int mt=0;mt<4;mt++){ for (int r=0;r<4;r++){
      float v = acc[nt][mt][r]; s1 += v; s2 = fmaf(v,v,s2);
    }}}
#pragma unroll
    for (int d=1; d<64; d<<=1){ s1 += __shfl_xor(s1,d); s2 += __shfl_xor(s2,d); }
    if (lane == 0){
      atomicAdd(&eS[((long)T*BB + b)*2],     s1);
      atomicAdd(&eS[((long)T*BB + b)*2 + 1], s2);
    }
    // store edges via LDS transpose -> coalesced global
#pragma unroll
    for (int mt=0;mt<4;mt++){
      int m = mt*16 + m15;
#pragma unroll
      for (int nt=0;nt<4;nt++){
        f32x4 v = acc[nt][mt];
        bf16x4 o = {(bf16)v[0],(bf16)v[1],(bf16)v[2],(bf16)v[3]};
        *(bf16x4*)(hb + sw128((unsigned)m, (unsigned)(nt*32+hi*8))) = o;
      }
    }
#pragma unroll
    for (int it=0; it<8; it++){
      int m = mrow + it*8;
      *(int4*)((char*)erow + m*128 + cbyte) = *(const int4*)(hb + sw128((unsigned)m, cbyte));
    }
  }
  // aggregation: agg[c,b,j,n] = sum_m out[n,m]
#pragma unroll
  for (int nt=0;nt<4;nt++){
    float p0 = acc[nt][0][0]+acc[nt][1][0]+acc[nt][2][0]+acc[nt][3][0];
    float p1 = acc[nt][0][1]+acc[nt][1][1]+acc[nt][2][1]+acc[nt][3][1];
    float p2 = acc[nt][0][2]+acc[nt][1][2]+acc[nt][2][2]+acc[nt][3][2];
    float p3 = acc[nt][0][3]+acc[nt][1][3]+acc[nt][2][3]+acc[nt][3][3];
    unsigned base = (unsigned)(nt*64 + hi*16);
    float2 q0 = {p0,p1}, q1 = {p2,p3};
    *(float2*)(hb + (unsigned)m15*256u + (base       ^ (((unsigned)(m15&7))<<4))) = q0;
    *(float2*)(hb + (unsigned)m15*256u + ((base+8u)  ^ (((unsigned)(m15&7))<<4))) = q1;
  }
  float s = 0.f;
#pragma unroll
  for (int r=0;r<16;r++){
    s += *(const float*)(hb + (unsigned)r*256u + ((((unsigned)lane)*4u) ^ (((unsigned)(r&7))<<4)));
  }
  agg[(cb*64 + j)*64 + lane] = s;
}

// =================== NODE A ===================
template<int T>
__global__ __launch_bounds__(256,2) void k_nodeA(const bf16* xn0,
    const bf16* xcur, const float* agg, float* xtilde, float* nS,
    const bf16* WTn0, const bf16* WTn1, const bf16* WTn2, const bf16* bc)
{
  int tid=threadIdx.x, lane=tid&63, w=tid>>6;
  int b = blockIdx.x, c = blockIdx.y;
  extern __shared__ char sm[];
  char* nin = sm;
  char* W0l = sm + 16384;
  char* W1l = sm + 32768;
  char* W2l = sm + 40960;
  char* hb  = sm + 49152 + w*2048;
  long cb = (long)c*BB + b;

#pragma unroll
  for (int q=0;q<2;q++){
    int idx = tid + q*256;
    int r = idx>>3; int e8 = (idx&7)*8;
    bf16x8 o;
    if (T==0) o = *(const bf16x8*)(xn0 + ((long)b*64 + r)*64 + e8);
    else      o = *(const bf16x8*)(xcur + (cb*64 + r)*64 + e8);
    *(bf16x8*)(nin + sw256((unsigned)r, (unsigned)(e8*2))) = o;
  }
#pragma unroll
  for (int q=0;q<2;q++){
    int idx = tid + q*256;
    int r = idx>>3; int e8 = (idx&7)*8;
    const float* ap = agg + (cb*64 + r)*64 + e8;
    float4 x = *(const float4*)ap; float4 y = *(const float4*)(ap+4);
    bf16x8 o = {(bf16)x.x,(bf16)x.y,(bf16)x.z,(bf16)x.w,(bf16)y.x,(bf16)y.y,(bf16)y.z,(bf16)y.w};
    *(bf16x8*)(nin + sw256((unsigned)r, (unsigned)(128 + e8*2))) = o;
  }
  stage128(W0l, WTn0 + (long)(T*CC+c)*8192, tid);
  stage64 (W1l, WTn1 + (long)(T*CC+c)*4096, tid);
  stage64 (W2l, WTn2 + (long)(T*CC+c)*4096, tid);
  __syncthreads();

  int hi=lane>>4, m15=lane&15;
  int m0 = w*16;
  long bofs = (long)(T*CC+c)*64;
  f32x4 a1[4][1];
  accBias<1>(bc + BC_NB0 + bofs, lane, a1);
  {
    bf16x8 bv[4];
#pragma unroll
    for (int ks=0;ks<4;ks++) bv[ks] = frd256(nin, m0+m15, ks, lane);
#pragma unroll
    for (int nt=0;nt<4;nt++){
#pragma unroll
      for (int ks=0;ks<4;ks++){
        bf16x8 av = frd256(W0l, nt*16+m15, ks, lane);
        a1[nt][0] = MFMA16(av, bv[ks], a1[nt][0]);
      }
    }
  }
  epiRelu<1>(hb, lane, a1);
  f32x4 a2[4][1];
  accBias<1>(bc + BC_NB1 + bofs, lane, a2);
  gemm64<1>(W1l, hb, lane, a2);
  epiRelu<1>(hb, lane, a2);
  f32x4 a3[4][1];
  accBias<1>(bc + BC_NB2 + bofs, lane, a3);
  gemm64<1>(W2l, hb, lane, a3);
  float s1=0.f, s2=0.f;
#pragma unroll
  for (int nt=0;nt<4;nt++){
#pragma unroll
    for (int r=0;r<4;r++){
      float v = a3[nt][0][r];
      s1 += v; s2 = fmaf(v,v,s2);
    }
  }
#pragma unroll
  for (int d=1; d<64; d<<=1){ s1 += __shfl_xor(s1,d); s2 += __shfl_xor(s2,d); }
  if (lane == 0){
    atomicAdd(&nS[((long)T*BB + b)*2],     s1);
    atomicAdd(&nS[((long)T*BB + b)*2 + 1], s2);
  }
#pragma unroll
  for (int nt=0;nt<4;nt++)
    *(f32x4*)(xtilde + (cb*64 + m0 + m15)*64 + nt*16 + hi*4) = a3[nt][0];
}

// =================== NODE B ===================
template<int T>
__global__ __launch_bounds__(256,2) void k_nodeB(
    const float* xtilde, const float* nS, const bf16* lnnW, const bf16* lnnB,
    bf16* xcur, bf16* Xd, bf16* Xs,
    const bf16* WTpd, const bf16* WTps, const bf16* bc,
    const float* eS, float2* eMR)
{
  int tid=threadIdx.x, lane=tid&63, w=tid>>6;
  int b = blockIdx.x;
  extern __shared__ char sm[];
  char* xl = sm;
  char* Wp = sm + 16384;
  // finalize edge-LN stats for this b (consumed by edge<T+1>)
  if (tid == 0 && T < 2){
    float2 st = *(const float2*)(eS + ((long)T*BB + b)*2);
    float mu = st.x * EDGE_CNT_INV;
    float rs = rsqrtf(st.y * EDGE_CNT_INV - mu*mu + LNEPS);
    eMR[(long)T*BB + b] = make_float2(mu, rs);
  }
  float2 st = *(const float2*)(nS + ((long)T*BB + b)*2);
  float mu = st.x * NODE_CNT_INV;
  float rs = rsqrtf(st.y * NODE_CNT_INV - mu*mu + LNEPS);
  {
    int r = tid>>1, k0 = (tid&1)*32;
    int cc = r>>6, node = r&63;
    const float* xt = xtilde + (((long)cc*BB + b)*64 + node)*64 + k0;
    long lnofs = (((long)T*CC + cc)*64 + node)*64 + k0;
    bf16* xc = xcur + (((long)cc*BB + b)*64 + node)*64 + k0;
#pragma unroll
    for (int u=0;u<32;u+=8){
      float4 xa = *(const float4*)(xt+u); float4 xb = *(const float4*)(xt+u+4);
      bf16x8 wv8 = *(const bf16x8*)(lnnW + lnofs + u);
      bf16x8 bv8 = *(const bf16x8*)(lnnB + lnofs + u);
      float x8[8] = {xa.x,xa.y,xa.z,xa.w,xb.x,xb.y,xb.z,xb.w};
      bf16x8 o;
#pragma unroll
      for (int q=0;q<8;q++) o[q] = (bf16)((x8[q]-mu)*rs*(float)wv8[q] + (float)bv8[q]);
      *(bf16x8*)(xc + u) = o;
      *(bf16x8*)(xl + sw128((unsigned)r, (unsigned)((k0+u)*2))) = o;
    }
  }
  stage64(Wp,         WTpd + (long)((T+1)*CC+0)*4096, tid);
  stage64(Wp + 8192,  WTps + (long)((T+1)*CC+0)*4096, tid);
  stage64(Wp + 16384, WTpd + (long)((T+1)*CC+1)*4096, tid);
  stage64(Wp + 24576, WTps + (long)((T+1)*CC+1)*4096, tid);
  __syncthreads();
  int c = w>>1, p = w&1;
  f32x4 acc[4][4];
  if (p==0) accBias<4>(bc + BC_EB0R + (T*CC+c)*64, lane, acc);
  else accZero<4>(acc);
  gemm64<4>(Wp + (c*2+p)*8192, xl + c*64*128, lane, acc);
  int hi=lane>>4, m15=lane&15;
  bf16* dst = (p==0 ? Xd : Xs) + ((long)c*BB + b)*64*64;
#pragma unroll
  for (int nt=0;nt<4;nt++){
#pragma unroll
    for (int mt=0;mt<4;mt++){
      f32x4 v = acc[nt][mt];
      bf16x4 o = {(bf16)v[0],(bf16)v[1],(bf16)v[2],(bf16)v[3]};
      *(bf16x4*)(dst + (long)(mt*16+m15)*64 + nt*16+hi*4) = o;
    }
  }
}

// =================== FINAL ===================
__global__ __launch_bounds__(256,2) void k_final(
    const float* xtilde, const float* nS, const bf16* lnnW, const bf16* lnnB,
    const int* flag, void* dout)
{
  bool b16 = flag[0] != 0;
  int tid = threadIdx.x; int b = blockIdx.x;
  float2 st = *(const float2*)(nS + ((long)2*BB + b)*2);
  float mu = st.x * NODE_CNT_INV;
  float rs = rsqrtf(st.y * NODE_CNT_INV - mu*mu + LNEPS);
  int r = tid>>2, k0 = (tid&3)*16;
  float o16[16];
#pragma unroll
  for (int u=0;u<16;u++) o16[u] = 0.f;
#pragma unroll
  for (int c=0;c<2;c++){
    const float* xt = xtilde + (((long)c*BB + b)*64 + r)*64 + k0;
    long lnofs = (((long)2*CC + c)*64 + r)*64 + k0;
#pragma unroll
    for (int u=0;u<16;u+=8){
      float4 xa = *(const float4*)(xt+u); float4 xb = *(const float4*)(xt+u+4);
      bf16x8 wv8 = *(const bf16x8*)(lnnW + lnofs + u);
      bf16x8 bv8 = *(const bf16x8*)(lnnB + lnofs + u);
      float x8[8] = {xa.x,xa.y,xa.z,xa.w,xb.x,xb.y,xb.z,xb.w};
#pragma unroll
      for (int q=0;q<8;q++) o16[u+q] += (x8[q]-mu)*rs*(float)wv8[q] + (float)bv8[q];
    }
  }
  long oofs = ((long)b*64 + r)*64 + k0;
  if (b16){
    bf16x8 v0, v1;
#pragma unroll
    for (int q=0;q<8;q++){ v0[q]=(bf16)o16[q]; v1[q]=(bf16)o16[8+q]; }
    *(bf16x8*)((bf16*)dout + oofs) = v0;
    *(bf16x8*)((bf16*)dout + oofs + 8) = v1;
  } else {
    float* f = (float*)dout + oofs;
#pragma unroll
    for (int q=0;q<4;q++){
      float4 v = {o16[q*4+0], o16[q*4+1], o16[q*4+2], o16[q*4+3]};
      *(float4*)(f + q*4) = v;
    }
  }
}

// =================== host ===================
extern "C" void kernel_launch(void* const* d_in, const int* in_sizes, int n_in,
                              void* d_out, int out_size, void* d_ws, size_t ws_size,
                              hipStream_t stream)
{
  (void)in_sizes; (void)n_in; (void)out_size;
  const void* nodes = d_in[0];
  const void* eW0f = d_in[3];  const void* eb0f = d_in[4];
  const void* eW0r = d_in[5];  const void* eb0r = d_in[6];
  const void* eW1  = d_in[7];  const void* eb1  = d_in[8];
  const void* eW2  = d_in[9];  const void* eb2  = d_in[10];
  const void* nW0  = d_in[11]; const void* nb0  = d_in[12];
  const void* nW1  = d_in[13]; const void* nb1  = d_in[14];
  const void* nW2  = d_in[15]; const void* nb2  = d_in[16];
  const void* ln_nw = d_in[17]; const void* ln_nb = d_in[18];
  const void* ln_ew = d_in[19]; const void* ln_eb = d_in[20];

  char* ws = (char*)d_ws;
  size_t off = 0;
  auto A = [&](size_t n){ size_t o = off; off += (n + 255) & ~(size_t)255; return o; };
  size_t edgesO = A((size_t)CC*BB*EPAD*64*2);
  size_t XdO  = A((size_t)CC*BB*64*64*2);
  size_t XsO  = A((size_t)CC*BB*64*64*2);
  size_t xtO  = A((size_t)CC*BB*64*64*4);
  size_t aggO = A((size_t)CC*BB*64*64*4);
  size_t xcO  = A((size_t)CC*BB*64*64*2);
  size_t lnwO = A((size_t)2*CC*EPAD*64*2);
  size_t lnbO = A((size_t)2*CC*EPAD*64*2);
  size_t WTpdO = A((size_t)3*CC*4096*2);
  size_t WTpsO = A((size_t)3*CC*4096*2);
  size_t WTe0eO = A((size_t)2*CC*4096*2);
  size_t WTe1O = A((size_t)3*CC*4096*2);
  size_t WTe2O = A((size_t)3*CC*4096*2);
  size_t WTn0O = A((size_t)3*CC*8192*2);
  size_t WTn1O = A((size_t)3*CC*4096*2);
  size_t WTn2O = A((size_t)3*CC*4096*2);
  size_t eSO = A((size_t)2*BB*2*4);
  size_t nSO = A((size_t)3*BB*2*4);
  size_t xn0O = A((size_t)BB*64*64*2);
  size_t lnnWO = A((size_t)3*CC*64*64*2);
  size_t lnnBO = A((size_t)3*CC*64*64*2);
  size_t bcO = A((size_t)BC_TOT*2);
  size_t flagO = A(4);
  size_t eMRO = A((size_t)2*BB*8);
  if (ws_size < off) return;

  bf16* edges = (bf16*)(ws+edgesO);
  bf16* Xd = (bf16*)(ws+XdO);  bf16* Xs = (bf16*)(ws+XsO);
  float* xt = (float*)(ws+xtO);  float* agg = (float*)(ws+aggO);
  bf16* xc = (bf16*)(ws+xcO);
  bf16* lnwP = (bf16*)(ws+lnwO); bf16* lnbP = (bf16*)(ws+lnbO);
  bf16* WTpd = (bf16*)(ws+WTpdO); bf16* WTps = (bf16*)(ws+WTpsO);
  bf16* WTe0e = (bf16*)(ws+WTe0eO); bf16* WTe1 = (bf16*)(ws+WTe1O); bf16* WTe2 = (bf16*)(ws+WTe2O);
  bf16* WTn0 = (bf16*)(ws+WTn0O); bf16* WTn1 = (bf16*)(ws+WTn1O); bf16* WTn2 = (bf16*)(ws+WTn2O);
  float* eS = (float*)(ws+eSO); float* nS = (float*)(ws+nSO);
  bf16* xn0 = (bf16*)(ws+xn0O);
  bf16* lnnW = (bf16*)(ws+lnnWO); bf16* lnnB = (bf16*)(ws+lnnBO);
  bf16* bc = (bf16*)(ws+bcO); int* flag = (int*)(ws+flagO);
  float2* eMR = (float2*)(ws+eMRO);

  hipMemsetAsync(ws+eSO, 0, (size_t)2*BB*2*4, stream);
  hipMemsetAsync(ws+nSO, 0, (size_t)3*BB*2*4, stream);

  k_prep<<<379, 256, 0, stream>>>(nodes, eW0f, eW0r, eW1, eW2, nW0, nW1, nW2,
                                  ln_ew, ln_eb, ln_nw, ln_nb,
                                  eb0f, eb0r, eb1, eb2, nb0, nb1, nb2,
                                  WTpd, WTps, WTe0e, WTe1, WTe2, WTn0, WTn1, WTn2,
                                  lnwP, lnbP, xn0, lnnW, lnnB, bc, flag);
  k_p0<<<BB, 256, 40960, stream>>>(xn0, WTpd, WTps, bc, Xd, Xs);

  dim3 eg(16, BB, CC);
  dim3 ng(BB, CC);

  k_edge<0><<<eg, 256, 49152, stream>>>(edges, Xd, Xs, agg, eS, eMR, WTe0e, WTe1, WTe2, lnwP, lnbP, bc);
  k_nodeA<0><<<ng, 256, 57344, stream>>>(xn0, xc, agg, xt, nS, WTn0, WTn1, WTn2, bc);
  k_nodeB<0><<<BB, 256, 49152, stream>>>(xt, nS, lnnW, lnnB, xc, Xd, Xs, WTpd, WTps, bc, eS, eMR);

  k_edge<1><<<eg, 256, 49152, stream>>>(edges, Xd, Xs, agg, eS, eMR, WTe0e, WTe1, WTe2, lnwP, lnbP, bc);
  k_nodeA<1><<<ng, 256, 57344, stream>>>(xn0, xc, agg, xt, nS, WTn0, WTn1, WTn2, bc);
  k_nodeB<1><<<BB, 256, 49152, stream>>>(xt, nS, lnnW, lnnB, xc, Xd, Xs, WTpd, WTps, bc, eS, eMR);

  k_edge<2><<<eg, 256, 49152, stream>>>(edges, Xd, Xs, agg, eS, eMR, WTe0e, WTe1, WTe2, lnwP, lnbP, bc);
  k_nodeA<2><<<ng, 256, 57344, stream>>>(xn0, xc, agg, xt, nS, WTn0, WTn1, WTn2, bc);
  k_final<<<BB, 256, 0, stream>>>(xt, nS, lnnW, lnnB, flag, d_out);
}

// Round 12
// 366.746 us; speedup vs baseline: 1.0055x; 1.0055x over previous
//
#include <hip/hip_runtime.h>

typedef __bf16 bf16;
typedef __attribute__((ext_vector_type(8))) __bf16 bf16x8;
typedef __attribute__((ext_vector_type(4))) __bf16 bf16x4;
typedef __attribute__((ext_vector_type(4))) float f32x4;

#define MFMA16(a,b,c) __builtin_amdgcn_mfma_f32_16x16x32_bf16((a),(b),(c),0,0,0)

#define CC 2
#define BB 128
#define EPAD 4096           // 64 dst * 64 padded src-rows
#define EDGE_CNT_INV (1.0f/516096.0f)   // C*4032*64
#define NODE_CNT_INV (1.0f/8192.0f)     // C*64*64
#define LNEPS 1e-5f

// bias pack offsets (elements) in bc[]
#define BC_EB0F 0
#define BC_EB0R 128
#define BC_EB1  384
#define BC_EB2  768
#define BC_NB0  1152
#define BC_NB1  1536
#define BC_NB2  1920
#define BC_TOT  2304

static __device__ __forceinline__ f32x4 zf4(){ f32x4 z = {0.f,0.f,0.f,0.f}; return z; }

// ---- dtype hedge (used ONLY in k_prep) ----
static __device__ __forceinline__ bool detectBf16(const void* p){
  const unsigned short* u = (const unsigned short*)p;
  int ok = 0;
#pragma unroll
  for (int i = 0; i < 64; ++i){
    unsigned v = u[i];
    unsigned e = (v >> 7) & 0xFFu;
    ok += (int)(((e >= 100u) && (e <= 150u)) || (v == 0u));
  }
  return ok >= 58;
}

static __device__ __forceinline__ float ldS(const void* p, long i, bool b16){
  return b16 ? (float)(((const bf16*)p)[i]) : ((const float*)p)[i];
}
static __device__ __forceinline__ void ld8(const void* p, long i, bool b16, float* o){
  if (b16){
    bf16x8 v = *(const bf16x8*)((const bf16*)p + i);
#pragma unroll
    for (int u=0;u<8;u++) o[u] = (float)v[u];
  } else {
    const float* f = (const float*)p + i;
    float4 a = *(const float4*)f; float4 b = *(const float4*)(f+4);
    o[0]=a.x;o[1]=a.y;o[2]=a.z;o[3]=a.w;o[4]=b.x;o[5]=b.y;o[6]=b.z;o[7]=b.w;
  }
}

// ---- LDS swizzles ----
static __device__ __forceinline__ unsigned sw128(unsigned row, unsigned cb){
  return row*128u + (cb ^ ((row&7u)<<4));
}
static __device__ __forceinline__ unsigned sw256(unsigned row, unsigned cb){
  return row*256u + (cb ^ ((row&7u)<<4));
}

static __device__ __forceinline__ void stage64(char* lds, const bf16* src, int tid){
#pragma unroll
  for (int q=0;q<2;q++){
    int idx = tid + q*256;
    int r = idx>>3; unsigned cb = (unsigned)((idx&7)*16);
    *(int4*)(lds + sw128((unsigned)r, cb)) = *(const int4*)((const char*)src + r*128 + cb);
  }
}
static __device__ __forceinline__ void stage128(char* lds, const bf16* src, int tid){
#pragma unroll
  for (int q=0;q<4;q++){
    int idx = tid + q*256;
    int r = idx>>4; unsigned cb = (unsigned)((idx&15)*16);
    *(int4*)(lds + sw256((unsigned)r, cb)) = *(const int4*)((const char*)src + r*256 + cb);
  }
}

static __device__ __forceinline__ bf16x8 frd64(const char* p, int row, int ks, int lane){
  return *(const bf16x8*)(p + sw128((unsigned)row, (unsigned)(ks*64 + ((lane>>4)<<4))));
}
static __device__ __forceinline__ bf16x8 frd256(const char* p, int row, int ks, int lane){
  return *(const bf16x8*)(p + sw256((unsigned)row, (unsigned)(ks*64 + ((lane>>4)<<4))));
}

// GEMM with A-fragments in registers; B from LDS
template<int NMT>
static __device__ __forceinline__ void gemmR(const bf16x8 (&af)[4][2], const char* hlds, int lane, f32x4 (*acc)[NMT]){
  int m15 = lane & 15;
#pragma unroll
  for (int mt=0;mt<NMT;mt++){
    bf16x8 b0 = frd64(hlds, mt*16+m15, 0, lane);
    bf16x8 b1 = frd64(hlds, mt*16+m15, 1, lane);
#pragma unroll
    for (int nt=0;nt<4;nt++){
      acc[nt][mt] = MFMA16(af[nt][0], b0, acc[nt][mt]);
      acc[nt][mt] = MFMA16(af[nt][1], b1, acc[nt][mt]);
    }
  }
}
// GEMM with A from LDS
template<int NMT>
static __device__ __forceinline__ void gemm64(const char* wlds, const char* hlds, int lane, f32x4 (*acc)[NMT]){
  int m15 = lane & 15;
  bf16x8 af[4][2];
#pragma unroll
  for (int nt=0;nt<4;nt++){
    af[nt][0] = frd64(wlds, nt*16+m15, 0, lane);
    af[nt][1] = frd64(wlds, nt*16+m15, 1, lane);
  }
#pragma unroll
  for (int mt=0;mt<NMT;mt++){
    bf16x8 b0 = frd64(hlds, mt*16+m15, 0, lane);
    bf16x8 b1 = frd64(hlds, mt*16+m15, 1, lane);
#pragma unroll
    for (int nt=0;nt<4;nt++){
      acc[nt][mt] = MFMA16(af[nt][0], b0, acc[nt][mt]);
      acc[nt][mt] = MFMA16(af[nt][1], b1, acc[nt][mt]);
    }
  }
}

template<int NMT>
static __device__ __forceinline__ void accZero(f32x4 (*acc)[NMT]){
#pragma unroll
  for (int a=0;a<4;a++){ for (int m=0;m<NMT;m++) acc[a][m] = zf4(); }
}
template<int NMT>
static __device__ __forceinline__ void accBias(const bf16* bias, int lane, f32x4 (*acc)[NMT]){
  int hi = lane>>4;
#pragma unroll
  for (int nt=0;nt<4;nt++){
    f32x4 bv;
#pragma unroll
    for (int r=0;r<4;r++) bv[r] = (float)bias[nt*16 + hi*4 + r];
#pragma unroll
    for (int mt=0;mt<NMT;mt++) acc[nt][mt] = bv;
  }
}
template<int NMT>
static __device__ __forceinline__ void epiRelu(char* hlds, int lane, f32x4 (*acc)[NMT]){
  int hi = lane>>4, m15 = lane&15;
#pragma unroll
  for (int nt=0;nt<4;nt++){
#pragma unroll
    for (int mt=0;mt<NMT;mt++){
      f32x4 v = acc[nt][mt];
      bf16x4 o;
#pragma unroll
      for (int r=0;r<4;r++){
        float t = v[r];
        t = t > 0.f ? t : 0.f;
        o[r] = (bf16)t;
      }
      *(bf16x4*)(hlds + sw128((unsigned)(mt*16+m15), (unsigned)(nt*32 + hi*8))) = o;
    }
  }
}

// =================== PREP ===================
__global__ void k_prep(const void* nodes,
    const void* eW0f, const void* eW0r, const void* eW1, const void* eW2,
    const void* nW0, const void* nW1, const void* nW2,
    const void* ln_ew, const void* ln_eb, const void* ln_nw, const void* ln_nb,
    const void* eb0f, const void* eb0r, const void* eb1, const void* eb2,
    const void* nb0, const void* nb1, const void* nb2,
    bf16* WTpd, bf16* WTps, bf16* WTe0e, bf16* WTe1, bf16* WTe2,
    bf16* WTn0, bf16* WTn1, bf16* WTn2,
    bf16* lnwP, bf16* lnbP,
    bf16* xn0, bf16* lnnW, bf16* lnnB, bf16* bc, int* flag)
{
  bool b16 = detectBf16(nodes);
  int tid = threadIdx.x, blk = blockIdx.x;
  if (blk < 256){
    int t = blk>>7, c = (blk>>6)&1, j = blk&63;
    int k = tid>>2, part = tid&3;
    long dofs = (((long)(t*CC + c))*EPAD + j*64 + k)*64 + part*16;
    if (k < 63){
      int i = k + (k>=j ? 1 : 0);
      int eref = i*63 + j - (j>i ? 1 : 0);
      long sofs = (((long)(t*CC + c))*4032 + eref)*64 + part*16;
      float o[8]; bf16x8 v;
      ld8(ln_ew, sofs,   b16, o); for (int u=0;u<8;u++) v[u]=(bf16)o[u]; *(bf16x8*)(lnwP+dofs)   = v;
      ld8(ln_ew, sofs+8, b16, o); for (int u=0;u<8;u++) v[u]=(bf16)o[u]; *(bf16x8*)(lnwP+dofs+8) = v;
      ld8(ln_eb, sofs,   b16, o); for (int u=0;u<8;u++) v[u]=(bf16)o[u]; *(bf16x8*)(lnbP+dofs)   = v;
      ld8(ln_eb, sofs+8, b16, o); for (int u=0;u<8;u++) v[u]=(bf16)o[u]; *(bf16x8*)(lnbP+dofs+8) = v;
    } else {
      bf16x8 z; for (int u=0;u<8;u++) z[u]=(bf16)0.f;
      *(bf16x8*)(lnwP+dofs)=z; *(bf16x8*)(lnwP+dofs+8)=z;
      *(bf16x8*)(lnbP+dofs)=z; *(bf16x8*)(lnbP+dofs+8)=z;
    }
    return;
  }
  int job = blk - 256;
  if (job < 46){
    const void* src = nullptr; bf16* dst = nullptr; int K = 64; long so = 0;
    if (job < 6){        int t=job>>1, c=job&1; dst = WTpd + (long)(t*CC+c)*4096;
      if (t==0){ src=eW0f; so=(long)c*128*64; } else { src=eW0r; so=((long)(t-1)*CC+c)*192*64; } }
    else if (job < 12){  int q=job-6; int t=q>>1,c=q&1; dst = WTps + (long)(t*CC+c)*4096;
      if (t==0){ src=eW0f; so=(long)c*128*64 + 64*64; } else { src=eW0r; so=((long)(t-1)*CC+c)*192*64 + 64*64; } }
    else if (job < 16){  int q=job-12; int t=q>>1,c=q&1; dst=WTe0e + (long)(t*CC+c)*4096; src=eW0r; so=((long)t*CC+c)*192*64 + 128*64; }
    else if (job < 22){  int q=job-16; int t=q>>1,c=q&1; dst=WTe1 + (long)(t*CC+c)*4096; src=eW1; so=((long)t*CC+c)*4096; }
    else if (job < 28){  int q=job-22; int t=q>>1,c=q&1; dst=WTe2 + (long)(t*CC+c)*4096; src=eW2; so=((long)t*CC+c)*4096; }
    else if (job < 34){  int q=job-28; int t=q>>1,c=q&1; dst=WTn0 + (long)(t*CC+c)*8192; src=nW0; so=((long)t*CC+c)*128*64; K=128; }
    else if (job < 40){  int q=job-34; int t=q>>1,c=q&1; dst=WTn1 + (long)(t*CC+c)*4096; src=nW1; so=((long)t*CC+c)*4096; }
    else              {  int q=job-40; int t=q>>1,c=q&1; dst=WTn2 + (long)(t*CC+c)*4096; src=nW2; so=((long)t*CC+c)*4096; }
    for (int idx = tid; idx < K*64; idx += 256){
      int n = idx & 63, k = idx >> 6;
      dst[(long)n*K + k] = (bf16)ldS(src, so + (long)k*64 + n, b16);
    }
  } else if (job < 110){
    long base = (long)(job-46)*8192;
#pragma unroll
    for (int k=0;k<4;k++){
      long o = base + k*2048 + tid*8;
      float t[8]; ld8(nodes, o, b16, t);
      bf16x8 v;
#pragma unroll
      for (int u=0;u<8;u++) v[u]=(bf16)t[u];
      *(bf16x8*)(xn0 + o) = v;
    }
  } else if (job < 122){
    int q = job-110;
    const void* src = (q<6) ? ln_nw : ln_nb;
    bf16* dst = (q<6) ? lnnW : lnnB;
    long base = (long)(q%6)*4096;
#pragma unroll
    for (int k=0;k<2;k++){
      long o = base + k*2048 + tid*8;
      float t[8]; ld8(src, o, b16, t);
      bf16x8 v;
#pragma unroll
      for (int u=0;u<8;u++) v[u]=(bf16)t[u];
      *(bf16x8*)(dst + o) = v;
    }
  } else {
    for (int idx = tid; idx < BC_TOT; idx += 256){
      float v;
      if      (idx < BC_EB0R) v = ldS(eb0f, idx - BC_EB0F, b16);
      else if (idx < BC_EB1 ) v = ldS(eb0r, idx - BC_EB0R, b16);
      else if (idx < BC_EB2 ) v = ldS(eb1,  idx - BC_EB1,  b16);
      else if (idx < BC_NB0 ) v = ldS(eb2,  idx - BC_EB2,  b16);
      else if (idx < BC_NB1 ) v = ldS(nb0,  idx - BC_NB0,  b16);
      else if (idx < BC_NB2 ) v = ldS(nb1,  idx - BC_NB1,  b16);
      else                    v = ldS(nb2,  idx - BC_NB2,  b16);
      bc[idx] = (bf16)v;
    }
    if (tid == 0) flag[0] = b16 ? 1 : 0;
  }
}

// =================== P0: Xd/Xs (bf16) = nodes@W0d + b0 / nodes@W0s ===================
__global__ __launch_bounds__(256,2) void k_p0(const bf16* xn0,
    const bf16* WTpd, const bf16* WTps, const bf16* bc, bf16* Xd, bf16* Xs)
{
  int tid=threadIdx.x, lane=tid&63, w=tid>>6;
  int b = blockIdx.x;
  extern __shared__ char sm[];
  char* xn = sm;
  char* Wp = sm + 8192;
  stage64(xn, xn0 + (long)b*4096, tid);
  stage64(Wp,         WTpd + 0,    tid);
  stage64(Wp + 8192,  WTps + 0,    tid);
  stage64(Wp + 16384, WTpd + 4096, tid);
  stage64(Wp + 24576, WTps + 4096, tid);
  __syncthreads();
  int c = w>>1, p = w&1;
  f32x4 acc[4][4];
  if (p==0) accBias<4>(bc + BC_EB0F + c*64, lane, acc);
  else accZero<4>(acc);
  gemm64<4>(Wp + (c*2+p)*8192, xn, lane, acc);
  int hi=lane>>4, m15=lane&15;
  bf16* dst = (p==0 ? Xd : Xs) + ((long)c*BB + b)*64*64;
#pragma unroll
  for (int nt=0;nt<4;nt++){
#pragma unroll
    for (int mt=0;mt<4;mt++){
      f32x4 v = acc[nt][mt];
      bf16x4 o = {(bf16)v[0],(bf16)v[1],(bf16)v[2],(bf16)v[3]};
      *(bf16x4*)(dst + (long)(mt*16+m15)*64 + nt*16+hi*4) = o;
    }
  }
}

// =================== EDGE kernel ===================
// 48KB LDS -> 3 blocks/CU. ALL of a chain's global reads (pe/lwv/lbv + af0 + xdv)
// issued in one prefetch phase at kernel start; normalize waits only on the first
// 24, GEMM0's af0 has ~400cyc slack. Peak regs ~147 < 170 cap (launch_bounds 256,3).
template<int T>
__global__ __launch_bounds__(256,3) void k_edge(
    bf16* edges, const bf16* Xd, const bf16* Xs, float* agg, float* eS,
    const float2* eMR,
    const bf16* WTe0e, const bf16* WTe1, const bf16* WTe2,
    const bf16* lnwP, const bf16* lnbP, const bf16* bc)
{
  int tid=threadIdx.x, lane=tid&63, w=tid>>6;
  int jt = blockIdx.x, b = blockIdx.y, c = blockIdx.z;
  int j = jt*4 + w;
  extern __shared__ char sm[];
  char* Wl1 = sm;
  char* Wl2 = sm + 8192;
  char* hb  = sm + 16384 + w*8192;     // per-wave [64][64] bf16

  long cb = (long)c*BB + b;
  int hi = lane>>4, m15 = lane&15;
  int mrow = lane>>3;
  unsigned cbyte = (unsigned)((lane&7)*16);
  int cbk = (lane&7)*8;

  bf16* erow = edges + (cb*EPAD + (long)j*64)*64;
  const bf16* xdrow = Xd + (cb*64 + j)*64;
  const bf16* xsbase = Xs + cb*64*64;

  // hoisted per-(T,b) LN stats
  float mu = 0.f, rs = 0.f;
  if (T>0){ float2 mr = eMR[(T-1)*BB + b]; mu = mr.x; rs = mr.y; }

  // ---- prefetch phase: ALL chain inputs issued up-front ----
  bf16x8 pe[8], lwv[8], lbv[8];
  bf16x8 af0[4][2];
  bf16x4 xdv[4];
  if (T>0){
    const char* lw = (const char*)(lnwP + (((long)(T-1)*CC+c)*EPAD + (long)j*64)*64);
    const char* lb = (const char*)(lnbP + (((long)(T-1)*CC+c)*EPAD + (long)j*64)*64);
#pragma unroll
    for (int it=0; it<8; it++){
      pe[it]  = *(const bf16x8*)((const char*)erow + (mrow+it*8)*128 + cbyte);
      lwv[it] = *(const bf16x8*)(lw + (mrow+it*8)*128 + cbyte);
      lbv[it] = *(const bf16x8*)(lb + (mrow+it*8)*128 + cbyte);
    }
    const bf16* w0 = WTe0e + (long)((T-1)*CC+c)*4096;
#pragma unroll
    for (int nt=0;nt<4;nt++){
#pragma unroll
      for (int ks=0;ks<2;ks++)
        af0[nt][ks] = *(const bf16x8*)(w0 + (nt*16+m15)*64 + ks*32 + hi*8);
    }
#pragma unroll
    for (int nt=0;nt<4;nt++) xdv[nt] = *(const bf16x4*)(xdrow + nt*16 + hi*4);
  }
  // T==0: Xd row prefetch (bf16)
  bf16x8 xd8v;
  if (T==0) xd8v = *(const bf16x8*)(xdrow + cbk);

  // stage weights to LDS (block-invariant)
  stage64(Wl1, WTe1 + (long)(T*CC+c)*4096, tid);
  stage64(Wl2, WTe2 + (long)(T*CC+c)*4096, tid);
  __syncthreads();

  f32x4 acc[4][4];

  if (T==0){
    float xd8[8];
#pragma unroll
    for (int u=0;u<8;u++) xd8[u] = (float)xd8v[u];
#pragma unroll
    for (int it=0; it<8; it++){
      int m = mrow + it*8;
      int i = m + (m>=j ? 1 : 0); if (i>63) i = 63;
      bf16x8 y8 = *(const bf16x8*)(xsbase + (long)i*64 + cbk);
      bf16x8 o;
#pragma unroll
      for (int u=0;u<8;u++){
        float tt = xd8[u] + (float)y8[u];
        tt = tt > 0.f ? tt : 0.f;
        o[u] = (bf16)tt;
      }
      *(bf16x8*)(hb + sw128((unsigned)m, (unsigned)(cbk*2))) = o;
    }
    accBias<4>(bc + BC_EB1 + (T*CC+c)*64, lane, acc);
    gemm64<4>(Wl1, hb, lane, acc);
    epiRelu<4>(hb, lane, acc);
    accBias<4>(bc + BC_EB2 + (T*CC+c)*64, lane, acc);
    gemm64<4>(Wl2, hb, lane, acc);
  } else {
    // normalize prefetched edges -> hb (frees pe/lwv/lbv)
#pragma unroll
    for (int it=0; it<8; it++){
      int m = mrow + it*8;
      bf16x8 e = pe[it];
      bf16x8 o;
#pragma unroll
      for (int u=0;u<8;u++){
        float tt = ((float)e[u] - mu) * rs;
        tt = tt * (float)lwv[it][u] + (float)lbv[it][u];
        o[u] = (bf16)tt;
      }
      *(bf16x8*)(hb + sw128((unsigned)m, cbyte)) = o;
    }
    // epilogue0 Xs operands (consumed after GEMM0; hidden under it)
    bf16x4 xsv[4][4];
#pragma unroll
    for (int mt=0;mt<4;mt++){
      int m = mt*16 + m15;
      int i = m + (m>=j ? 1 : 0); if (i>63) i=63;
#pragma unroll
      for (int nt=0;nt<4;nt++)
        xsv[mt][nt] = *(const bf16x4*)(xsbase + (long)i*64 + nt*16 + hi*4);
    }
    accZero<4>(acc);
    gemmR<4>(af0, hb, lane, acc);
    // epilogue0: + Xd'[j] + Xs[i(m)], relu -> h0
#pragma unroll
    for (int mt=0;mt<4;mt++){
      int m = mt*16 + m15;
#pragma unroll
      for (int nt=0;nt<4;nt++){
        f32x4 v = acc[nt][mt];
        float t0 = v[0] + (float)xdv[nt][0] + (float)xsv[mt][nt][0];
        float t1 = v[1] + (float)xdv[nt][1] + (float)xsv[mt][nt][1];
        float t2 = v[2] + (float)xdv[nt][2] + (float)xsv[mt][nt][2];
        float t3 = v[3] + (float)xdv[nt][3] + (float)xsv[mt][nt][3];
        bf16x4 o;
        o[0] = (bf16)(t0>0.f?t0:0.f); o[1] = (bf16)(t1>0.f?t1:0.f);
        o[2] = (bf16)(t2>0.f?t2:0.f); o[3] = (bf16)(t3>0.f?t3:0.f);
        *(bf16x4*)(hb + sw128((unsigned)m, (unsigned)(nt*32+hi*8))) = o;
      }
    }
    accBias<4>(bc + BC_EB1 + (T*CC+c)*64, lane, acc);
    gemm64<4>(Wl1, hb, lane, acc);
    epiRelu<4>(hb, lane, acc);
    accBias<4>(bc + BC_EB2 + (T*CC+c)*64, lane, acc);
    gemm64<4>(Wl2, hb, lane, acc);
  }

  // ---- final epilogue ----
  if (m15 == 15){
#pragma unroll
    for (int nt=0;nt<4;nt++) acc[nt][3] = zf4();
  }
  if (T < 2){
    float s1=0.f, s2=0.f;
#pragma unroll
    for (int nt=0;nt<4;nt++){ for (int mt=0;mt<4;mt++){ for (int r=0;r<4;r++){
      float v = acc[nt][mt][r]; s1 += v; s2 = fmaf(v,v,s2);
    }}}
#pragma unroll
    for (int d=1; d<64; d<<=1){ s1 += __shfl_xor(s1,d); s2 += __shfl_xor(s2,d); }
    if (lane == 0){
      atomicAdd(&eS[((long)T*BB + b)*2],     s1);
      atomicAdd(&eS[((long)T*BB + b)*2 + 1], s2);
    }
    // store edges via LDS transpose -> coalesced global
#pragma unroll
    for (int mt=0;mt<4;mt++){
      int m = mt*16 + m15;
#pragma unroll
      for (int nt=0;nt<4;nt++){
        f32x4 v = acc[nt][mt];
        bf16x4 o = {(bf16)v[0],(bf16)v[1],(bf16)v[2],(bf16)v[3]};
        *(bf16x4*)(hb + sw128((unsigned)m, (unsigned)(nt*32+hi*8))) = o;
      }
    }
#pragma unroll
    for (int it=0; it<8; it++){
      int m = mrow + it*8;
      *(int4*)((char*)erow + m*128 + cbyte) = *(const int4*)(hb + sw128((unsigned)m, cbyte));
    }
  }
  // aggregation: agg[c,b,j,n] = sum_m out[n,m]
#pragma unroll
  for (int nt=0;nt<4;nt++){
    float p0 = acc[nt][0][0]+acc[nt][1][0]+acc[nt][2][0]+acc[nt][3][0];
    float p1 = acc[nt][0][1]+acc[nt][1][1]+acc[nt][2][1]+acc[nt][3][1];
    float p2 = acc[nt][0][2]+acc[nt][1][2]+acc[nt][2][2]+acc[nt][3][2];
    float p3 = acc[nt][0][3]+acc[nt][1][3]+acc[nt][2][3]+acc[nt][3][3];
    unsigned base = (unsigned)(nt*64 + hi*16);
    float2 q0 = {p0,p1}, q1 = {p2,p3};
    *(float2*)(hb + (unsigned)m15*256u + (base       ^ (((unsigned)(m15&7))<<4))) = q0;
    *(float2*)(hb + (unsigned)m15*256u + ((base+8u)  ^ (((unsigned)(m15&7))<<4))) = q1;
  }
  float s = 0.f;
#pragma unroll
  for (int r=0;r<16;r++){
    s += *(const float*)(hb + (unsigned)r*256u + ((((unsigned)lane)*4u) ^ (((unsigned)(r&7))<<4)));
  }
  agg[(cb*64 + j)*64 + lane] = s;
}

// =================== NODE A ===================
template<int T>
__global__ __launch_bounds__(256,2) void k_nodeA(const bf16* xn0,
    const bf16* xcur, const float* agg, float* xtilde, float* nS,
    const bf16* WTn0, const bf16* WTn1, const bf16* WTn2, const bf16* bc)
{
  int tid=threadIdx.x, lane=tid&63, w=tid>>6;
  int b = blockIdx.x, c = blockIdx.y;
  extern __shared__ char sm[];
  char* nin = sm;
  char* W0l = sm + 16384;
  char* W1l = sm + 32768;
  char* W2l = sm + 40960;
  char* hb  = sm + 49152 + w*2048;
  long cb = (long)c*BB + b;

#pragma unroll
  for (int q=0;q<2;q++){
    int idx = tid + q*256;
    int r = idx>>3; int e8 = (idx&7)*8;
    bf16x8 o;
    if (T==0) o = *(const bf16x8*)(xn0 + ((long)b*64 + r)*64 + e8);
    else      o = *(const bf16x8*)(xcur + (cb*64 + r)*64 + e8);
    *(bf16x8*)(nin + sw256((unsigned)r, (unsigned)(e8*2))) = o;
  }
#pragma unroll
  for (int q=0;q<2;q++){
    int idx = tid + q*256;
    int r = idx>>3; int e8 = (idx&7)*8;
    const float* ap = agg + (cb*64 + r)*64 + e8;
    float4 x = *(const float4*)ap; float4 y = *(const float4*)(ap+4);
    bf16x8 o = {(bf16)x.x,(bf16)x.y,(bf16)x.z,(bf16)x.w,(bf16)y.x,(bf16)y.y,(bf16)y.z,(bf16)y.w};
    *(bf16x8*)(nin + sw256((unsigned)r, (unsigned)(128 + e8*2))) = o;
  }
  stage128(W0l, WTn0 + (long)(T*CC+c)*8192, tid);
  stage64 (W1l, WTn1 + (long)(T*CC+c)*4096, tid);
  stage64 (W2l, WTn2 + (long)(T*CC+c)*4096, tid);
  __syncthreads();

  int hi=lane>>4, m15=lane&15;
  int m0 = w*16;
  long bofs = (long)(T*CC+c)*64;
  f32x4 a1[4][1];
  accBias<1>(bc + BC_NB0 + bofs, lane, a1);
  {
    bf16x8 bv[4];
#pragma unroll
    for (int ks=0;ks<4;ks++) bv[ks] = frd256(nin, m0+m15, ks, lane);
#pragma unroll
    for (int nt=0;nt<4;nt++){
#pragma unroll
      for (int ks=0;ks<4;ks++){
        bf16x8 av = frd256(W0l, nt*16+m15, ks, lane);
        a1[nt][0] = MFMA16(av, bv[ks], a1[nt][0]);
      }
    }
  }
  epiRelu<1>(hb, lane, a1);
  f32x4 a2[4][1];
  accBias<1>(bc + BC_NB1 + bofs, lane, a2);
  gemm64<1>(W1l, hb, lane, a2);
  epiRelu<1>(hb, lane, a2);
  f32x4 a3[4][1];
  accBias<1>(bc + BC_NB2 + bofs, lane, a3);
  gemm64<1>(W2l, hb, lane, a3);
  float s1=0.f, s2=0.f;
#pragma unroll
  for (int nt=0;nt<4;nt++){
#pragma unroll
    for (int r=0;r<4;r++){
      float v = a3[nt][0][r];
      s1 += v; s2 = fmaf(v,v,s2);
    }
  }
#pragma unroll
  for (int d=1; d<64; d<<=1){ s1 += __shfl_xor(s1,d); s2 += __shfl_xor(s2,d); }
  if (lane == 0){
    atomicAdd(&nS[((long)T*BB + b)*2],     s1);
    atomicAdd(&nS[((long)T*BB + b)*2 + 1], s2);
  }
#pragma unroll
  for (int nt=0;nt<4;nt++)
    *(f32x4*)(xtilde + (cb*64 + m0 + m15)*64 + nt*16 + hi*4) = a3[nt][0];
}

// =================== NODE B ===================
template<int T>
__global__ __launch_bounds__(256,2) void k_nodeB(
    const float* xtilde, const float* nS, const bf16* lnnW, const bf16* lnnB,
    bf16* xcur, bf16* Xd, bf16* Xs,
    const bf16* WTpd, const bf16* WTps, const bf16* bc,
    const float* eS, float2* eMR)
{
  int tid=threadIdx.x, lane=tid&63, w=tid>>6;
  int b = blockIdx.x;
  extern __shared__ char sm[];
  char* xl = sm;
  char* Wp = sm + 16384;
  // finalize edge-LN stats for this b (consumed by edge<T+1>)
  if (tid == 0 && T < 2){
    float2 st = *(const float2*)(eS + ((long)T*BB + b)*2);
    float mu = st.x * EDGE_CNT_INV;
    float rs = rsqrtf(st.y * EDGE_CNT_INV - mu*mu + LNEPS);
    eMR[(long)T*BB + b] = make_float2(mu, rs);
  }
  float2 st = *(const float2*)(nS + ((long)T*BB + b)*2);
  float mu = st.x * NODE_CNT_INV;
  float rs = rsqrtf(st.y * NODE_CNT_INV - mu*mu + LNEPS);
  {
    int r = tid>>1, k0 = (tid&1)*32;
    int cc = r>>6, node = r&63;
    const float* xt = xtilde + (((long)cc*BB + b)*64 + node)*64 + k0;
    long lnofs = (((long)T*CC + cc)*64 + node)*64 + k0;
    bf16* xc = xcur + (((long)cc*BB + b)*64 + node)*64 + k0;
#pragma unroll
    for (int u=0;u<32;u+=8){
      float4 xa = *(const float4*)(xt+u); float4 xb = *(const float4*)(xt+u+4);
      bf16x8 wv8 = *(const bf16x8*)(lnnW + lnofs + u);
      bf16x8 bv8 = *(const bf16x8*)(lnnB + lnofs + u);
      float x8[8] = {xa.x,xa.y,xa.z,xa.w,xb.x,xb.y,xb.z,xb.w};
      bf16x8 o;
#pragma unroll
      for (int q=0;q<8;q++) o[q] = (bf16)((x8[q]-mu)*rs*(float)wv8[q] + (float)bv8[q]);
      *(bf16x8*)(xc + u) = o;
      *(bf16x8*)(xl + sw128((unsigned)r, (unsigned)((k0+u)*2))) = o;
    }
  }
  stage64(Wp,         WTpd + (long)((T+1)*CC+0)*4096, tid);
  stage64(Wp + 8192,  WTps + (long)((T+1)*CC+0)*4096, tid);
  stage64(Wp + 16384, WTpd + (long)((T+1)*CC+1)*4096, tid);
  stage64(Wp + 24576, WTps + (long)((T+1)*CC+1)*4096, tid);
  __syncthreads();
  int c = w>>1, p = w&1;
  f32x4 acc[4][4];
  if (p==0) accBias<4>(bc + BC_EB0R + (T*CC+c)*64, lane, acc);
  else accZero<4>(acc);
  gemm64<4>(Wp + (c*2+p)*8192, xl + c*64*128, lane, acc);
  int hi=lane>>4, m15=lane&15;
  bf16* dst = (p==0 ? Xd : Xs) + ((long)c*BB + b)*64*64;
#pragma unroll
  for (int nt=0;nt<4;nt++){
#pragma unroll
    for (int mt=0;mt<4;mt++){
      f32x4 v = acc[nt][mt];
      bf16x4 o = {(bf16)v[0],(bf16)v[1],(bf16)v[2],(bf16)v[3]};
      *(bf16x4*)(dst + (long)(mt*16+m15)*64 + nt*16+hi*4) = o;
    }
  }
}

// =================== FINAL ===================
__global__ __launch_bounds__(256,2) void k_final(
    const float* xtilde, const float* nS, const bf16* lnnW, const bf16* lnnB,
    const int* flag, void* dout)
{
  bool b16 = flag[0] != 0;
  int tid = threadIdx.x; int b = blockIdx.x;
  float2 st = *(const float2*)(nS + ((long)2*BB + b)*2);
  float mu = st.x * NODE_CNT_INV;
  float rs = rsqrtf(st.y * NODE_CNT_INV - mu*mu + LNEPS);
  int r = tid>>2, k0 = (tid&3)*16;
  float o16[16];
#pragma unroll
  for (int u=0;u<16;u++) o16[u] = 0.f;
#pragma unroll
  for (int c=0;c<2;c++){
    const float* xt = xtilde + (((long)c*BB + b)*64 + r)*64 + k0;
    long lnofs = (((long)2*CC + c)*64 + r)*64 + k0;
#pragma unroll
    for (int u=0;u<16;u+=8){
      float4 xa = *(const float4*)(xt+u); float4 xb = *(const float4*)(xt+u+4);
      bf16x8 wv8 = *(const bf16x8*)(lnnW + lnofs + u);
      bf16x8 bv8 = *(const bf16x8*)(lnnB + lnofs + u);
      float x8[8] = {xa.x,xa.y,xa.z,xa.w,xb.x,xb.y,xb.z,xb.w};
#pragma unroll
      for (int q=0;q<8;q++) o16[u+q] += (x8[q]-mu)*rs*(float)wv8[q] + (float)bv8[q];
    }
  }
  long oofs = ((long)b*64 + r)*64 + k0;
  if (b16){
    bf16x8 v0, v1;
#pragma unroll
    for (int q=0;q<8;q++){ v0[q]=(bf16)o16[q]; v1[q]=(bf16)o16[8+q]; }
    *(bf16x8*)((bf16*)dout + oofs) = v0;
    *(bf16x8*)((bf16*)dout + oofs + 8) = v1;
  } else {
    float* f = (float*)dout + oofs;
#pragma unroll
    for (int q=0;q<4;q++){
      float4 v = {o16[q*4+0], o16[q*4+1], o16[q*4+2], o16[q*4+3]};
      *(float4*)(f + q*4) = v;
    }
  }
}

// =================== host ===================
extern "C" void kernel_launch(void* const* d_in, const int* in_sizes, int n_in,
                              void* d_out, int out_size, void* d_ws, size_t ws_size,
                              hipStream_t stream)
{
  (void)in_sizes; (void)n_in; (void)out_size;
  const void* nodes = d_in[0];
  const void* eW0f = d_in[3];  const void* eb0f = d_in[4];
  const void* eW0r = d_in[5];  const void* eb0r = d_in[6];
  const void* eW1  = d_in[7];  const void* eb1  = d_in[8];
  const void* eW2  = d_in[9];  const void* eb2  = d_in[10];
  const void* nW0  = d_in[11]; const void* nb0  = d_in[12];
  const void* nW1  = d_in[13]; const void* nb1  = d_in[14];
  const void* nW2  = d_in[15]; const void* nb2  = d_in[16];
  const void* ln_nw = d_in[17]; const void* ln_nb = d_in[18];
  const void* ln_ew = d_in[19]; const void* ln_eb = d_in[20];

  char* ws = (char*)d_ws;
  size_t off = 0;
  auto A = [&](size_t n){ size_t o = off; off += (n + 255) & ~(size_t)255; return o; };
  size_t edgesO = A((size_t)CC*BB*EPAD*64*2);
  size_t XdO  = A((size_t)CC*BB*64*64*2);
  size_t XsO  = A((size_t)CC*BB*64*64*2);
  size_t xtO  = A((size_t)CC*BB*64*64*4);
  size_t aggO = A((size_t)CC*BB*64*64*4);
  size_t xcO  = A((size_t)CC*BB*64*64*2);
  size_t lnwO = A((size_t)2*CC*EPAD*64*2);
  size_t lnbO = A((size_t)2*CC*EPAD*64*2);
  size_t WTpdO = A((size_t)3*CC*4096*2);
  size_t WTpsO = A((size_t)3*CC*4096*2);
  size_t WTe0eO = A((size_t)2*CC*4096*2);
  size_t WTe1O = A((size_t)3*CC*4096*2);
  size_t WTe2O = A((size_t)3*CC*4096*2);
  size_t WTn0O = A((size_t)3*CC*8192*2);
  size_t WTn1O = A((size_t)3*CC*4096*2);
  size_t WTn2O = A((size_t)3*CC*4096*2);
  size_t eSO = A((size_t)2*BB*2*4);
  size_t nSO = A((size_t)3*BB*2*4);
  size_t xn0O = A((size_t)BB*64*64*2);
  size_t lnnWO = A((size_t)3*CC*64*64*2);
  size_t lnnBO = A((size_t)3*CC*64*64*2);
  size_t bcO = A((size_t)BC_TOT*2);
  size_t flagO = A(4);
  size_t eMRO = A((size_t)2*BB*8);
  if (ws_size < off) return;

  bf16* edges = (bf16*)(ws+edgesO);
  bf16* Xd = (bf16*)(ws+XdO);  bf16* Xs = (bf16*)(ws+XsO);
  float* xt = (float*)(ws+xtO);  float* agg = (float*)(ws+aggO);
  bf16* xc = (bf16*)(ws+xcO);
  bf16* lnwP = (bf16*)(ws+lnwO); bf16* lnbP = (bf16*)(ws+lnbO);
  bf16* WTpd = (bf16*)(ws+WTpdO); bf16* WTps = (bf16*)(ws+WTpsO);
  bf16* WTe0e = (bf16*)(ws+WTe0eO); bf16* WTe1 = (bf16*)(ws+WTe1O); bf16* WTe2 = (bf16*)(ws+WTe2O);
  bf16* WTn0 = (bf16*)(ws+WTn0O); bf16* WTn1 = (bf16*)(ws+WTn1O); bf16* WTn2 = (bf16*)(ws+WTn2O);
  float* eS = (float*)(ws+eSO); float* nS = (float*)(ws+nSO);
  bf16* xn0 = (bf16*)(ws+xn0O);
  bf16* lnnW = (bf16*)(ws+lnnWO); bf16* lnnB = (bf16*)(ws+lnnBO);
  bf16* bc = (bf16*)(ws+bcO); int* flag = (int*)(ws+flagO);
  float2* eMR = (float2*)(ws+eMRO);

  hipMemsetAsync(ws+eSO, 0, (size_t)2*BB*2*4, stream);
  hipMemsetAsync(ws+nSO, 0, (size_t)3*BB*2*4, stream);

  k_prep<<<379, 256, 0, stream>>>(nodes, eW0f, eW0r, eW1, eW2, nW0, nW1, nW2,
                                  ln_ew, ln_eb, ln_nw, ln_nb,
                                  eb0f, eb0r, eb1, eb2, nb0, nb1, nb2,
                                  WTpd, WTps, WTe0e, WTe1, WTe2, WTn0, WTn1, WTn2,
                                  lnwP, lnbP, xn0, lnnW, lnnB, bc, flag);
  k_p0<<<BB, 256, 40960, stream>>>(xn0, WTpd, WTps, bc, Xd, Xs);

  dim3 eg(16, BB, CC);
  dim3 ng(BB, CC);

  k_edge<0><<<eg, 256, 49152, stream>>>(edges, Xd, Xs, agg, eS, eMR, WTe0e, WTe1, WTe2, lnwP, lnbP, bc);
  k_nodeA<0><<<ng, 256, 57344, stream>>>(xn0, xc, agg, xt, nS, WTn0, WTn1, WTn2, bc);
  k_nodeB<0><<<BB, 256, 49152, stream>>>(xt, nS, lnnW, lnnB, xc, Xd, Xs, WTpd, WTps, bc, eS, eMR);

  k_edge<1><<<eg, 256, 49152, stream>>>(edges, Xd, Xs, agg, eS, eMR, WTe0e, WTe1, WTe2, lnwP, lnbP, bc);
  k_nodeA<1><<<ng, 256, 57344, stream>>>(xn0, xc, agg, xt, nS, WTn0, WTn1, WTn2, bc);
  k_nodeB<1><<<BB, 256, 49152, stream>>>(xt, nS, lnnW, lnnB, xc, Xd, Xs, WTpd, WTps, bc, eS, eMR);

  k_edge<2><<<eg, 256, 49152, stream>>>(edges, Xd, Xs, agg, eS, eMR, WTe0e, WTe1, WTe2, lnwP, lnbP, bc);
  k_nodeA<2><<<ng, 256, 57344, stream>>>(xn0, xc, agg, xt, nS, WTn0, WTn1, WTn2, bc);
  k_final<<<BB, 256, 0, stream>>>(xt, nS, lnnW, lnnB, flag, d_out);
}

// Round 13
// 289.875 us; speedup vs baseline: 1.2721x; 1.2652x over previous
//
#include <hip/hip_runtime.h>

typedef __bf16 bf16;
typedef __attribute__((ext_vector_type(8))) __bf16 bf16x8;
typedef __attribute__((ext_vector_type(4))) __bf16 bf16x4;
typedef __attribute__((ext_vector_type(4))) float f32x4;

#define MFMA16(a,b,c) __builtin_amdgcn_mfma_f32_16x16x32_bf16((a),(b),(c),0,0,0)

#define CC 2
#define BB 128
#define EPAD 4096           // 64 dst * 64 padded src-rows
#define EDGE_CNT_INV (1.0f/516096.0f)   // C*4032*64
#define NODE_CNT_INV (1.0f/8192.0f)     // C*64*64
#define LNEPS 1e-5f

// bias pack offsets (elements) in bc[]
#define BC_EB0F 0
#define BC_EB0R 128
#define BC_EB1  384
#define BC_EB2  768
#define BC_NB0  1152
#define BC_NB1  1536
#define BC_NB2  1920
#define BC_TOT  2304

static __device__ __forceinline__ f32x4 zf4(){ f32x4 z = {0.f,0.f,0.f,0.f}; return z; }

// async global->LDS DMA, 16B per lane; LDS dest = base + lane*16 (HW), src per-lane
static __device__ __forceinline__ void dma16(char* lds, const char* g){
  __builtin_amdgcn_global_load_lds(
    (const __attribute__((address_space(1))) unsigned int*)g,
    (__attribute__((address_space(3))) unsigned int*)lds,
    16, 0, 0);
}

// ---- dtype hedge (used ONLY in k_prep) ----
static __device__ __forceinline__ bool detectBf16(const void* p){
  const unsigned short* u = (const unsigned short*)p;
  int ok = 0;
#pragma unroll
  for (int i = 0; i < 64; ++i){
    unsigned v = u[i];
    unsigned e = (v >> 7) & 0xFFu;
    ok += (int)(((e >= 100u) && (e <= 150u)) || (v == 0u));
  }
  return ok >= 58;
}

static __device__ __forceinline__ float ldS(const void* p, long i, bool b16){
  return b16 ? (float)(((const bf16*)p)[i]) : ((const float*)p)[i];
}
static __device__ __forceinline__ void ld8(const void* p, long i, bool b16, float* o){
  if (b16){
    bf16x8 v = *(const bf16x8*)((const bf16*)p + i);
#pragma unroll
    for (int u=0;u<8;u++) o[u] = (float)v[u];
  } else {
    const float* f = (const float*)p + i;
    float4 a = *(const float4*)f; float4 b = *(const float4*)(f+4);
    o[0]=a.x;o[1]=a.y;o[2]=a.z;o[3]=a.w;o[4]=b.x;o[5]=b.y;o[6]=b.z;o[7]=b.w;
  }
}

// ---- LDS swizzles ----
static __device__ __forceinline__ unsigned sw128(unsigned row, unsigned cb){
  return row*128u + (cb ^ ((row&7u)<<4));
}
static __device__ __forceinline__ unsigned sw256(unsigned row, unsigned cb){
  return row*256u + (cb ^ ((row&7u)<<4));
}

static __device__ __forceinline__ void stage64(char* lds, const bf16* src, int tid){
#pragma unroll
  for (int q=0;q<2;q++){
    int idx = tid + q*256;
    int r = idx>>3; unsigned cb = (unsigned)((idx&7)*16);
    *(int4*)(lds + sw128((unsigned)r, cb)) = *(const int4*)((const char*)src + r*128 + cb);
  }
}
static __device__ __forceinline__ void stage128(char* lds, const bf16* src, int tid){
#pragma unroll
  for (int q=0;q<4;q++){
    int idx = tid + q*256;
    int r = idx>>4; unsigned cb = (unsigned)((idx&15)*16);
    *(int4*)(lds + sw256((unsigned)r, cb)) = *(const int4*)((const char*)src + r*256 + cb);
  }
}
// linear 8KB stage (no swizzle)
static __device__ __forceinline__ void stageLin(char* lds, const char* src, int tid){
#pragma unroll
  for (int q=0;q<2;q++){
    int idx = tid + q*256;
    *(int4*)(lds + idx*16) = *(const int4*)(src + idx*16);
  }
}

static __device__ __forceinline__ bf16x8 frd64(const char* p, int row, int ks, int lane){
  return *(const bf16x8*)(p + sw128((unsigned)row, (unsigned)(ks*64 + ((lane>>4)<<4))));
}
static __device__ __forceinline__ bf16x8 frd256(const char* p, int row, int ks, int lane){
  return *(const bf16x8*)(p + sw256((unsigned)row, (unsigned)(ks*64 + ((lane>>4)<<4))));
}

// GEMM with A from LDS
template<int NMT>
static __device__ __forceinline__ void gemm64(const char* wlds, const char* hlds, int lane, f32x4 (*acc)[NMT]){
  int m15 = lane & 15;
  bf16x8 af[4][2];
#pragma unroll
  for (int nt=0;nt<4;nt++){
    af[nt][0] = frd64(wlds, nt*16+m15, 0, lane);
    af[nt][1] = frd64(wlds, nt*16+m15, 1, lane);
  }
#pragma unroll
  for (int mt=0;mt<NMT;mt++){
    bf16x8 b0 = frd64(hlds, mt*16+m15, 0, lane);
    bf16x8 b1 = frd64(hlds, mt*16+m15, 1, lane);
#pragma unroll
    for (int nt=0;nt<4;nt++){
      acc[nt][mt] = MFMA16(af[nt][0], b0, acc[nt][mt]);
      acc[nt][mt] = MFMA16(af[nt][1], b1, acc[nt][mt]);
    }
  }
}

template<int NMT>
static __device__ __forceinline__ void accZero(f32x4 (*acc)[NMT]){
#pragma unroll
  for (int a=0;a<4;a++){ for (int m=0;m<NMT;m++) acc[a][m] = zf4(); }
}
template<int NMT>
static __device__ __forceinline__ void accBias(const bf16* bias, int lane, f32x4 (*acc)[NMT]){
  int hi = lane>>4;
#pragma unroll
  for (int nt=0;nt<4;nt++){
    f32x4 bv;
#pragma unroll
    for (int r=0;r<4;r++) bv[r] = (float)bias[nt*16 + hi*4 + r];
#pragma unroll
    for (int mt=0;mt<NMT;mt++) acc[nt][mt] = bv;
  }
}
template<int NMT>
static __device__ __forceinline__ void epiRelu(char* hlds, int lane, f32x4 (*acc)[NMT]){
  int hi = lane>>4, m15 = lane&15;
#pragma unroll
  for (int nt=0;nt<4;nt++){
#pragma unroll
    for (int mt=0;mt<NMT;mt++){
      f32x4 v = acc[nt][mt];
      bf16x4 o;
#pragma unroll
      for (int r=0;r<4;r++){
        float t = v[r];
        t = t > 0.f ? t : 0.f;
        o[r] = (bf16)t;
      }
      *(bf16x4*)(hlds + sw128((unsigned)(mt*16+m15), (unsigned)(nt*32 + hi*8))) = o;
    }
  }
}

// =================== PREP ===================
__global__ void k_prep(const void* nodes,
    const void* eW0f, const void* eW0r, const void* eW1, const void* eW2,
    const void* nW0, const void* nW1, const void* nW2,
    const void* ln_ew, const void* ln_eb, const void* ln_nw, const void* ln_nb,
    const void* eb0f, const void* eb0r, const void* eb1, const void* eb2,
    const void* nb0, const void* nb1, const void* nb2,
    bf16* WTpd, bf16* WTps, bf16* WTe0e, bf16* WTe1, bf16* WTe2,
    bf16* WTn0, bf16* WTn1, bf16* WTn2,
    bf16* lnwP, bf16* lnbP,
    bf16* xn0, bf16* lnnW, bf16* lnnB, bf16* bc, int* flag)
{
  bool b16 = detectBf16(nodes);
  int tid = threadIdx.x, blk = blockIdx.x;
  if (blk < 256){
    int t = blk>>7, c = (blk>>6)&1, j = blk&63;
    int k = tid>>2, part = tid&3;
    long dofs = (((long)(t*CC + c))*EPAD + j*64 + k)*64 + part*16;
    if (k < 63){
      int i = k + (k>=j ? 1 : 0);
      int eref = i*63 + j - (j>i ? 1 : 0);
      long sofs = (((long)(t*CC + c))*4032 + eref)*64 + part*16;
      float o[8]; bf16x8 v;
      ld8(ln_ew, sofs,   b16, o); for (int u=0;u<8;u++) v[u]=(bf16)o[u]; *(bf16x8*)(lnwP+dofs)   = v;
      ld8(ln_ew, sofs+8, b16, o); for (int u=0;u<8;u++) v[u]=(bf16)o[u]; *(bf16x8*)(lnwP+dofs+8) = v;
      ld8(ln_eb, sofs,   b16, o); for (int u=0;u<8;u++) v[u]=(bf16)o[u]; *(bf16x8*)(lnbP+dofs)   = v;
      ld8(ln_eb, sofs+8, b16, o); for (int u=0;u<8;u++) v[u]=(bf16)o[u]; *(bf16x8*)(lnbP+dofs+8) = v;
    } else {
      bf16x8 z; for (int u=0;u<8;u++) z[u]=(bf16)0.f;
      *(bf16x8*)(lnwP+dofs)=z; *(bf16x8*)(lnwP+dofs+8)=z;
      *(bf16x8*)(lnbP+dofs)=z; *(bf16x8*)(lnbP+dofs+8)=z;
    }
    return;
  }
  int job = blk - 256;
  if (job < 46){
    const void* src = nullptr; bf16* dst = nullptr; int K = 64; long so = 0;
    if (job < 6){        int t=job>>1, c=job&1; dst = WTpd + (long)(t*CC+c)*4096;
      if (t==0){ src=eW0f; so=(long)c*128*64; } else { src=eW0r; so=((long)(t-1)*CC+c)*192*64; } }
    else if (job < 12){  int q=job-6; int t=q>>1,c=q&1; dst = WTps + (long)(t*CC+c)*4096;
      if (t==0){ src=eW0f; so=(long)c*128*64 + 64*64; } else { src=eW0r; so=((long)(t-1)*CC+c)*192*64 + 64*64; } }
    else if (job < 16){  int q=job-12; int t=q>>1,c=q&1; dst=WTe0e + (long)(t*CC+c)*4096; src=eW0r; so=((long)t*CC+c)*192*64 + 128*64; }
    else if (job < 22){  int q=job-16; int t=q>>1,c=q&1; dst=WTe1 + (long)(t*CC+c)*4096; src=eW1; so=((long)t*CC+c)*4096; }
    else if (job < 28){  int q=job-22; int t=q>>1,c=q&1; dst=WTe2 + (long)(t*CC+c)*4096; src=eW2; so=((long)t*CC+c)*4096; }
    else if (job < 34){  int q=job-28; int t=q>>1,c=q&1; dst=WTn0 + (long)(t*CC+c)*8192; src=nW0; so=((long)t*CC+c)*128*64; K=128; }
    else if (job < 40){  int q=job-34; int t=q>>1,c=q&1; dst=WTn1 + (long)(t*CC+c)*4096; src=nW1; so=((long)t*CC+c)*4096; }
    else              {  int q=job-40; int t=q>>1,c=q&1; dst=WTn2 + (long)(t*CC+c)*4096; src=nW2; so=((long)t*CC+c)*4096; }
    for (int idx = tid; idx < K*64; idx += 256){
      int n = idx & 63, k = idx >> 6;
      dst[(long)n*K + k] = (bf16)ldS(src, so + (long)k*64 + n, b16);
    }
  } else if (job < 110){
    long base = (long)(job-46)*8192;
#pragma unroll
    for (int k=0;k<4;k++){
      long o = base + k*2048 + tid*8;
      float t[8]; ld8(nodes, o, b16, t);
      bf16x8 v;
#pragma unroll
      for (int u=0;u<8;u++) v[u]=(bf16)t[u];
      *(bf16x8*)(xn0 + o) = v;
    }
  } else if (job < 122){
    int q = job-110;
    const void* src = (q<6) ? ln_nw : ln_nb;
    bf16* dst = (q<6) ? lnnW : lnnB;
    long base = (long)(q%6)*4096;
#pragma unroll
    for (int k=0;k<2;k++){
      long o = base + k*2048 + tid*8;
      float t[8]; ld8(src, o, b16, t);
      bf16x8 v;
#pragma unroll
      for (int u=0;u<8;u++) v[u]=(bf16)t[u];
      *(bf16x8*)(dst + o) = v;
    }
  } else {
    for (int idx = tid; idx < BC_TOT; idx += 256){
      float v;
      if      (idx < BC_EB0R) v = ldS(eb0f, idx - BC_EB0F, b16);
      else if (idx < BC_EB1 ) v = ldS(eb0r, idx - BC_EB0R, b16);
      else if (idx < BC_EB2 ) v = ldS(eb1,  idx - BC_EB1,  b16);
      else if (idx < BC_NB0 ) v = ldS(eb2,  idx - BC_EB2,  b16);
      else if (idx < BC_NB1 ) v = ldS(nb0,  idx - BC_NB0,  b16);
      else if (idx < BC_NB2 ) v = ldS(nb1,  idx - BC_NB1,  b16);
      else                    v = ldS(nb2,  idx - BC_NB2,  b16);
      bc[idx] = (bf16)v;
    }
    if (tid == 0) flag[0] = b16 ? 1 : 0;
  }
}

// =================== P0: Xd/Xs (bf16) = nodes@W0d + b0 / nodes@W0s ===================
__global__ __launch_bounds__(256,2) void k_p0(const bf16* xn0,
    const bf16* WTpd, const bf16* WTps, const bf16* bc, bf16* Xd, bf16* Xs)
{
  int tid=threadIdx.x, lane=tid&63, w=tid>>6;
  int b = blockIdx.x;
  extern __shared__ char sm[];
  char* xn = sm;
  char* Wp = sm + 8192;
  stage64(xn, xn0 + (long)b*4096, tid);
  stage64(Wp,         WTpd + 0,    tid);
  stage64(Wp + 8192,  WTps + 0,    tid);
  stage64(Wp + 16384, WTpd + 4096, tid);
  stage64(Wp + 24576, WTps + 4096, tid);
  __syncthreads();
  int c = w>>1, p = w&1;
  f32x4 acc[4][4];
  if (p==0) accBias<4>(bc + BC_EB0F + c*64, lane, acc);
  else accZero<4>(acc);
  gemm64<4>(Wp + (c*2+p)*8192, xn, lane, acc);
  int hi=lane>>4, m15=lane&15;
  bf16* dst = (p==0 ? Xd : Xs) + ((long)c*BB + b)*64*64;
#pragma unroll
  for (int nt=0;nt<4;nt++){
#pragma unroll
    for (int mt=0;mt<4;mt++){
      f32x4 v = acc[nt][mt];
      bf16x4 o = {(bf16)v[0],(bf16)v[1],(bf16)v[2],(bf16)v[3]};
      *(bf16x4*)(dst + (long)(mt*16+m15)*64 + nt*16+hi*4) = o;
    }
  }
}

// =================== EDGE kernel ===================
// Block = (j, bg, c); each wave loops 4 b. Weights + lnw/lnb (j,c-invariant) staged
// to LDS once per block. Edge tile DMA'd global->LDS via global_load_lds (zero VGPR,
// 8 ops in flight, one vmcnt drain) and normalized IN PLACE in hb (linear read,
// swizzled write, disjoint row sets per it). LDS: T>0 72KB (2 blk/CU), T=0 48KB.
template<int T>
__global__ __launch_bounds__(256,2) void k_edge(
    bf16* edges, const bf16* Xd, const bf16* Xs, float* agg, float* eS,
    const float2* eMR,
    const bf16* WTe0e, const bf16* WTe1, const bf16* WTe2,
    const bf16* lnwP, const bf16* lnbP, const bf16* bc)
{
  int tid=threadIdx.x, lane=tid&63, w=tid>>6;
  int j = blockIdx.x, bg = blockIdx.y, c = blockIdx.z;
  extern __shared__ char sm[];
  char* Wl1 = sm;
  char* Wl2 = sm + 8192;
  char* Wl0 = sm + 16384;            // T>0 only
  char* lwL = sm + 24576;            // T>0 only, linear [64][64]
  char* lbL = sm + 32768;
  char* hb  = sm + (T>0 ? 40960 : 16384) + w*8192;   // per-wave [64][64] bf16

  int hi = lane>>4, m15 = lane&15;
  int mrow = lane>>3;
  unsigned cbyte = (unsigned)((lane&7)*16);
  int cbk = (lane&7)*8;

  stage64(Wl1, WTe1 + (long)(T*CC+c)*4096, tid);
  stage64(Wl2, WTe2 + (long)(T*CC+c)*4096, tid);
  if (T>0){
    stage64(Wl0, WTe0e + (long)((T-1)*CC+c)*4096, tid);
    const char* lwg = (const char*)(lnwP + (((long)(T-1)*CC+c)*EPAD + (long)j*64)*64);
    const char* lbg = (const char*)(lnbP + (((long)(T-1)*CC+c)*EPAD + (long)j*64)*64);
    stageLin(lwL, lwg, tid);
    stageLin(lbL, lbg, tid);
  }
  __syncthreads();

  for (int t=0; t<4; t++){
    int b = bg*16 + w*4 + t;
    long cb = (long)c*BB + b;
    bf16* erow = edges + (cb*EPAD + (long)j*64)*64;
    const bf16* xdrow = Xd + (cb*64 + j)*64;
    const bf16* xsbase = Xs + cb*4096;

    f32x4 acc[4][4];

    if (T==0){
      bf16x8 xd8v = *(const bf16x8*)(xdrow + cbk);
      float xd8[8];
#pragma unroll
      for (int u=0;u<8;u++) xd8[u] = (float)xd8v[u];
#pragma unroll
      for (int it=0; it<8; it++){
        int m = mrow + it*8;
        int i = m + (m>=j ? 1 : 0); if (i>63) i = 63;
        bf16x8 y8 = *(const bf16x8*)(xsbase + (long)i*64 + cbk);
        bf16x8 o;
#pragma unroll
        for (int u=0;u<8;u++){
          float tt = xd8[u] + (float)y8[u];
          tt = tt > 0.f ? tt : 0.f;
          o[u] = (bf16)tt;
        }
        *(bf16x8*)(hb + sw128((unsigned)m, (unsigned)(cbk*2))) = o;
      }
      accBias<4>(bc + BC_EB1 + (T*CC+c)*64, lane, acc);
      gemm64<4>(Wl1, hb, lane, acc);
      epiRelu<4>(hb, lane, acc);
      accBias<4>(bc + BC_EB2 + (T*CC+c)*64, lane, acc);
      gemm64<4>(Wl2, hb, lane, acc);
    } else {
      float2 mr = eMR[(T-1)*BB + b];
      float mu = mr.x, rs = mr.y;
      // drain prior chain's hb reads, then DMA e tile into hb (zero VGPRs)
      asm volatile("s_waitcnt lgkmcnt(0)" ::: "memory");
#pragma unroll
      for (int it=0; it<8; it++)
        dma16(hb + it*1024, (const char*)erow + it*1024 + (long)lane*16);
      asm volatile("s_waitcnt vmcnt(0)" ::: "memory");
      __builtin_amdgcn_sched_barrier(0);
      // normalize in place: linear read -> swizzled write (same it-chunk)
#pragma unroll
      for (int it=0; it<8; it++){
        int m = mrow + it*8;
        bf16x8 e  = *(const bf16x8*)(hb  + lane*16 + it*1024);
        bf16x8 wv = *(const bf16x8*)(lwL + lane*16 + it*1024);
        bf16x8 bv = *(const bf16x8*)(lbL + lane*16 + it*1024);
        bf16x8 o;
#pragma unroll
        for (int u=0;u<8;u++){
          float tt = ((float)e[u] - mu) * rs;
          tt = tt * (float)wv[u] + (float)bv[u];
          o[u] = (bf16)tt;
        }
        *(bf16x8*)(hb + sw128((unsigned)m, cbyte)) = o;
      }
      // epilogue0 operands (hidden under GEMM0)
      bf16x4 xdv[4], xsv[4][4];
#pragma unroll
      for (int nt=0;nt<4;nt++) xdv[nt] = *(const bf16x4*)(xdrow + nt*16 + hi*4);
#pragma unroll
      for (int mt=0;mt<4;mt++){
        int m = mt*16 + m15;
        int i = m + (m>=j ? 1 : 0); if (i>63) i=63;
#pragma unroll
        for (int nt=0;nt<4;nt++)
          xsv[mt][nt] = *(const bf16x4*)(xsbase + (long)i*64 + nt*16 + hi*4);
      }
      accZero<4>(acc);
      gemm64<4>(Wl0, hb, lane, acc);
      // epilogue0: + Xd'[j] + Xs[i(m)], relu -> h0
#pragma unroll
      for (int mt=0;mt<4;mt++){
        int m = mt*16 + m15;
#pragma unroll
        for (int nt=0;nt<4;nt++){
          f32x4 v = acc[nt][mt];
          float t0 = v[0] + (float)xdv[nt][0] + (float)xsv[mt][nt][0];
          float t1 = v[1] + (float)xdv[nt][1] + (float)xsv[mt][nt][1];
          float t2 = v[2] + (float)xdv[nt][2] + (float)xsv[mt][nt][2];
          float t3 = v[3] + (float)xdv[nt][3] + (float)xsv[mt][nt][3];
          bf16x4 o;
          o[0] = (bf16)(t0>0.f?t0:0.f); o[1] = (bf16)(t1>0.f?t1:0.f);
          o[2] = (bf16)(t2>0.f?t2:0.f); o[3] = (bf16)(t3>0.f?t3:0.f);
          *(bf16x4*)(hb + sw128((unsigned)m, (unsigned)(nt*32+hi*8))) = o;
        }
      }
      accBias<4>(bc + BC_EB1 + (T*CC+c)*64, lane, acc);
      gemm64<4>(Wl1, hb, lane, acc);
      epiRelu<4>(hb, lane, acc);
      accBias<4>(bc + BC_EB2 + (T*CC+c)*64, lane, acc);
      gemm64<4>(Wl2, hb, lane, acc);
    }

    // ---- per-chain epilogue ----
    if (m15 == 15){
#pragma unroll
      for (int nt=0;nt<4;nt++) acc[nt][3] = zf4();
    }
    if (T < 2){
      float s1=0.f, s2=0.f;
#pragma unroll
      for (int nt=0;nt<4;nt++){ for (int mt=0;mt<4;mt++){ for (int r=0;r<4;r++){
        float v = acc[nt][mt][r]; s1 += v; s2 = fmaf(v,v,s2);
      }}}
#pragma unroll
      for (int d=1; d<64; d<<=1){ s1 += __shfl_xor(s1,d); s2 += __shfl_xor(s2,d); }
      if (lane == 0){
        atomicAdd(&eS[((long)T*BB + b)*2],     s1);
        atomicAdd(&eS[((long)T*BB + b)*2 + 1], s2);
      }
      // store edges via LDS transpose -> coalesced global
#pragma unroll
      for (int mt=0;mt<4;mt++){
        int m = mt*16 + m15;
#pragma unroll
        for (int nt=0;nt<4;nt++){
          f32x4 v = acc[nt][mt];
          bf16x4 o = {(bf16)v[0],(bf16)v[1],(bf16)v[2],(bf16)v[3]};
          *(bf16x4*)(hb + sw128((unsigned)m, (unsigned)(nt*32+hi*8))) = o;
        }
      }
#pragma unroll
      for (int it=0; it<8; it++){
        int m = mrow + it*8;
        *(int4*)((char*)erow + m*128 + cbyte) = *(const int4*)(hb + sw128((unsigned)m, cbyte));
      }
    }
    // aggregation: agg[c,b,j,n] = sum_m out[n,m]
#pragma unroll
    for (int nt=0;nt<4;nt++){
      float p0 = acc[nt][0][0]+acc[nt][1][0]+acc[nt][2][0]+acc[nt][3][0];
      float p1 = acc[nt][0][1]+acc[nt][1][1]+acc[nt][2][1]+acc[nt][3][1];
      float p2 = acc[nt][0][2]+acc[nt][1][2]+acc[nt][2][2]+acc[nt][3][2];
      float p3 = acc[nt][0][3]+acc[nt][1][3]+acc[nt][2][3]+acc[nt][3][3];
      unsigned base = (unsigned)(nt*64 + hi*16);
      float2 q0 = {p0,p1}, q1 = {p2,p3};
      *(float2*)(hb + (unsigned)m15*256u + (base       ^ (((unsigned)(m15&7))<<4))) = q0;
      *(float2*)(hb + (unsigned)m15*256u + ((base+8u)  ^ (((unsigned)(m15&7))<<4))) = q1;
    }
    float s = 0.f;
#pragma unroll
    for (int r=0;r<16;r++){
      s += *(const float*)(hb + (unsigned)r*256u + ((((unsigned)lane)*4u) ^ (((unsigned)(r&7))<<4)));
    }
    agg[(cb*64 + j)*64 + lane] = s;
  }
}

// =================== NODE A ===================
template<int T>
__global__ __launch_bounds__(256,2) void k_nodeA(const bf16* xn0,
    const bf16* xcur, const float* agg, float* xtilde, float* nS,
    const bf16* WTn0, const bf16* WTn1, const bf16* WTn2, const bf16* bc)
{
  int tid=threadIdx.x, lane=tid&63, w=tid>>6;
  int b = blockIdx.x, c = blockIdx.y;
  extern __shared__ char sm[];
  char* nin = sm;
  char* W0l = sm + 16384;
  char* W1l = sm + 32768;
  char* W2l = sm + 40960;
  char* hb  = sm + 49152 + w*2048;
  long cb = (long)c*BB + b;

#pragma unroll
  for (int q=0;q<2;q++){
    int idx = tid + q*256;
    int r = idx>>3; int e8 = (idx&7)*8;
    bf16x8 o;
    if (T==0) o = *(const bf16x8*)(xn0 + ((long)b*64 + r)*64 + e8);
    else      o = *(const bf16x8*)(xcur + (cb*64 + r)*64 + e8);
    *(bf16x8*)(nin + sw256((unsigned)r, (unsigned)(e8*2))) = o;
  }
#pragma unroll
  for (int q=0;q<2;q++){
    int idx = tid + q*256;
    int r = idx>>3; int e8 = (idx&7)*8;
    const float* ap = agg + (cb*64 + r)*64 + e8;
    float4 x = *(const float4*)ap; float4 y = *(const float4*)(ap+4);
    bf16x8 o = {(bf16)x.x,(bf16)x.y,(bf16)x.z,(bf16)x.w,(bf16)y.x,(bf16)y.y,(bf16)y.z,(bf16)y.w};
    *(bf16x8*)(nin + sw256((unsigned)r, (unsigned)(128 + e8*2))) = o;
  }
  stage128(W0l, WTn0 + (long)(T*CC+c)*8192, tid);
  stage64 (W1l, WTn1 + (long)(T*CC+c)*4096, tid);
  stage64 (W2l, WTn2 + (long)(T*CC+c)*4096, tid);
  __syncthreads();

  int hi=lane>>4, m15=lane&15;
  int m0 = w*16;
  long bofs = (long)(T*CC+c)*64;
  f32x4 a1[4][1];
  accBias<1>(bc + BC_NB0 + bofs, lane, a1);
  {
    bf16x8 bv[4];
#pragma unroll
    for (int ks=0;ks<4;ks++) bv[ks] = frd256(nin, m0+m15, ks, lane);
#pragma unroll
    for (int nt=0;nt<4;nt++){
#pragma unroll
      for (int ks=0;ks<4;ks++){
        bf16x8 av = frd256(W0l, nt*16+m15, ks, lane);
        a1[nt][0] = MFMA16(av, bv[ks], a1[nt][0]);
      }
    }
  }
  epiRelu<1>(hb, lane, a1);
  f32x4 a2[4][1];
  accBias<1>(bc + BC_NB1 + bofs, lane, a2);
  gemm64<1>(W1l, hb, lane, a2);
  epiRelu<1>(hb, lane, a2);
  f32x4 a3[4][1];
  accBias<1>(bc + BC_NB2 + bofs, lane, a3);
  gemm64<1>(W2l, hb, lane, a3);
  float s1=0.f, s2=0.f;
#pragma unroll
  for (int nt=0;nt<4;nt++){
#pragma unroll
    for (int r=0;r<4;r++){
      float v = a3[nt][0][r];
      s1 += v; s2 = fmaf(v,v,s2);
    }
  }
#pragma unroll
  for (int d=1; d<64; d<<=1){ s1 += __shfl_xor(s1,d); s2 += __shfl_xor(s2,d); }
  if (lane == 0){
    atomicAdd(&nS[((long)T*BB + b)*2],     s1);
    atomicAdd(&nS[((long)T*BB + b)*2 + 1], s2);
  }
#pragma unroll
  for (int nt=0;nt<4;nt++)
    *(f32x4*)(xtilde + (cb*64 + m0 + m15)*64 + nt*16 + hi*4) = a3[nt][0];
}

// =================== NODE B ===================
template<int T>
__global__ __launch_bounds__(256,2) void k_nodeB(
    const float* xtilde, const float* nS, const bf16* lnnW, const bf16* lnnB,
    bf16* xcur, bf16* Xd, bf16* Xs,
    const bf16* WTpd, const bf16* WTps, const bf16* bc,
    const float* eS, float2* eMR)
{
  int tid=threadIdx.x, lane=tid&63, w=tid>>6;
  int b = blockIdx.x;
  extern __shared__ char sm[];
  char* xl = sm;
  char* Wp = sm + 16384;
  // finalize edge-LN stats for this b (consumed by edge<T+1>)
  if (tid == 0 && T < 2){
    float2 st = *(const float2*)(eS + ((long)T*BB + b)*2);
    float mu = st.x * EDGE_CNT_INV;
    float rs = rsqrtf(st.y * EDGE_CNT_INV - mu*mu + LNEPS);
    eMR[(long)T*BB + b] = make_float2(mu, rs);
  }
  float2 st = *(const float2*)(nS + ((long)T*BB + b)*2);
  float mu = st.x * NODE_CNT_INV;
  float rs = rsqrtf(st.y * NODE_CNT_INV - mu*mu + LNEPS);
  {
    int r = tid>>1, k0 = (tid&1)*32;
    int cc = r>>6, node = r&63;
    const float* xt = xtilde + (((long)cc*BB + b)*64 + node)*64 + k0;
    long lnofs = (((long)T*CC + cc)*64 + node)*64 + k0;
    bf16* xc = xcur + (((long)cc*BB + b)*64 + node)*64 + k0;
#pragma unroll
    for (int u=0;u<32;u+=8){
      float4 xa = *(const float4*)(xt+u); float4 xb = *(const float4*)(xt+u+4);
      bf16x8 wv8 = *(const bf16x8*)(lnnW + lnofs + u);
      bf16x8 bv8 = *(const bf16x8*)(lnnB + lnofs + u);
      float x8[8] = {xa.x,xa.y,xa.z,xa.w,xb.x,xb.y,xb.z,xb.w};
      bf16x8 o;
#pragma unroll
      for (int q=0;q<8;q++) o[q] = (bf16)((x8[q]-mu)*rs*(float)wv8[q] + (float)bv8[q]);
      *(bf16x8*)(xc + u) = o;
      *(bf16x8*)(xl + sw128((unsigned)r, (unsigned)((k0+u)*2))) = o;
    }
  }
  stage64(Wp,         WTpd + (long)((T+1)*CC+0)*4096, tid);
  stage64(Wp + 8192,  WTps + (long)((T+1)*CC+0)*4096, tid);
  stage64(Wp + 16384, WTpd + (long)((T+1)*CC+1)*4096, tid);
  stage64(Wp + 24576, WTps + (long)((T+1)*CC+1)*4096, tid);
  __syncthreads();
  int c = w>>1, p = w&1;
  f32x4 acc[4][4];
  if (p==0) accBias<4>(bc + BC_EB0R + (T*CC+c)*64, lane, acc);
  else accZero<4>(acc);
  gemm64<4>(Wp + (c*2+p)*8192, xl + c*64*128, lane, acc);
  int hi=lane>>4, m15=lane&15;
  bf16* dst = (p==0 ? Xd : Xs) + ((long)c*BB + b)*64*64;
#pragma unroll
  for (int nt=0;nt<4;nt++){
#pragma unroll
    for (int mt=0;mt<4;mt++){
      f32x4 v = acc[nt][mt];
      bf16x4 o = {(bf16)v[0],(bf16)v[1],(bf16)v[2],(bf16)v[3]};
      *(bf16x4*)(dst + (long)(mt*16+m15)*64 + nt*16+hi*4) = o;
    }
  }
}

// =================== FINAL ===================
__global__ __launch_bounds__(256,2) void k_final(
    const float* xtilde, const float* nS, const bf16* lnnW, const bf16* lnnB,
    const int* flag, void* dout)
{
  bool b16 = flag[0] != 0;
  int tid = threadIdx.x; int b = blockIdx.x;
  float2 st = *(const float2*)(nS + ((long)2*BB + b)*2);
  float mu = st.x * NODE_CNT_INV;
  float rs = rsqrtf(st.y * NODE_CNT_INV - mu*mu + LNEPS);
  int r = tid>>2, k0 = (tid&3)*16;
  float o16[16];
#pragma unroll
  for (int u=0;u<16;u++) o16[u] = 0.f;
#pragma unroll
  for (int c=0;c<2;c++){
    const float* xt = xtilde + (((long)c*BB + b)*64 + r)*64 + k0;
    long lnofs = (((long)2*CC + c)*64 + r)*64 + k0;
#pragma unroll
    for (int u=0;u<16;u+=8){
      float4 xa = *(const float4*)(xt+u); float4 xb = *(const float4*)(xt+u+4);
      bf16x8 wv8 = *(const bf16x8*)(lnnW + lnofs + u);
      bf16x8 bv8 = *(const bf16x8*)(lnnB + lnofs + u);
      float x8[8] = {xa.x,xa.y,xa.z,xa.w,xb.x,xb.y,xb.z,xb.w};
#pragma unroll
      for (int q=0;q<8;q++) o16[u+q] += (x8[q]-mu)*rs*(float)wv8[q] + (float)bv8[q];
    }
  }
  long oofs = ((long)b*64 + r)*64 + k0;
  if (b16){
    bf16x8 v0, v1;
#pragma unroll
    for (int q=0;q<8;q++){ v0[q]=(bf16)o16[q]; v1[q]=(bf16)o16[8+q]; }
    *(bf16x8*)((bf16*)dout + oofs) = v0;
    *(bf16x8*)((bf16*)dout + oofs + 8) = v1;
  } else {
    float* f = (float*)dout + oofs;
#pragma unroll
    for (int q=0;q<4;q++){
      float4 v = {o16[q*4+0], o16[q*4+1], o16[q*4+2], o16[q*4+3]};
      *(float4*)(f + q*4) = v;
    }
  }
}

// =================== host ===================
extern "C" void kernel_launch(void* const* d_in, const int* in_sizes, int n_in,
                              void* d_out, int out_size, void* d_ws, size_t ws_size,
                              hipStream_t stream)
{
  (void)in_sizes; (void)n_in; (void)out_size;
  const void* nodes = d_in[0];
  const void* eW0f = d_in[3];  const void* eb0f = d_in[4];
  const void* eW0r = d_in[5];  const void* eb0r = d_in[6];
  const void* eW1  = d_in[7];  const void* eb1  = d_in[8];
  const void* eW2  = d_in[9];  const void* eb2  = d_in[10];
  const void* nW0  = d_in[11]; const void* nb0  = d_in[12];
  const void* nW1  = d_in[13]; const void* nb1  = d_in[14];
  const void* nW2  = d_in[15]; const void* nb2  = d_in[16];
  const void* ln_nw = d_in[17]; const void* ln_nb = d_in[18];
  const void* ln_ew = d_in[19]; const void* ln_eb = d_in[20];

  char* ws = (char*)d_ws;
  size_t off = 0;
  auto A = [&](size_t n){ size_t o = off; off += (n + 255) & ~(size_t)255; return o; };
  size_t edgesO = A((size_t)CC*BB*EPAD*64*2);
  size_t XdO  = A((size_t)CC*BB*64*64*2);
  size_t XsO  = A((size_t)CC*BB*64*64*2);
  size_t xtO  = A((size_t)CC*BB*64*64*4);
  size_t aggO = A((size_t)CC*BB*64*64*4);
  size_t xcO  = A((size_t)CC*BB*64*64*2);
  size_t lnwO = A((size_t)2*CC*EPAD*64*2);
  size_t lnbO = A((size_t)2*CC*EPAD*64*2);
  size_t WTpdO = A((size_t)3*CC*4096*2);
  size_t WTpsO = A((size_t)3*CC*4096*2);
  size_t WTe0eO = A((size_t)2*CC*4096*2);
  size_t WTe1O = A((size_t)3*CC*4096*2);
  size_t WTe2O = A((size_t)3*CC*4096*2);
  size_t WTn0O = A((size_t)3*CC*8192*2);
  size_t WTn1O = A((size_t)3*CC*4096*2);
  size_t WTn2O = A((size_t)3*CC*4096*2);
  size_t eSO = A((size_t)2*BB*2*4);
  size_t nSO = A((size_t)3*BB*2*4);
  size_t xn0O = A((size_t)BB*64*64*2);
  size_t lnnWO = A((size_t)3*CC*64*64*2);
  size_t lnnBO = A((size_t)3*CC*64*64*2);
  size_t bcO = A((size_t)BC_TOT*2);
  size_t flagO = A(4);
  size_t eMRO = A((size_t)2*BB*8);
  if (ws_size < off) return;

  bf16* edges = (bf16*)(ws+edgesO);
  bf16* Xd = (bf16*)(ws+XdO);  bf16* Xs = (bf16*)(ws+XsO);
  float* xt = (float*)(ws+xtO);  float* agg = (float*)(ws+aggO);
  bf16* xc = (bf16*)(ws+xcO);
  bf16* lnwP = (bf16*)(ws+lnwO); bf16* lnbP = (bf16*)(ws+lnbO);
  bf16* WTpd = (bf16*)(ws+WTpdO); bf16* WTps = (bf16*)(ws+WTpsO);
  bf16* WTe0e = (bf16*)(ws+WTe0eO); bf16* WTe1 = (bf16*)(ws+WTe1O); bf16* WTe2 = (bf16*)(ws+WTe2O);
  bf16* WTn0 = (bf16*)(ws+WTn0O); bf16* WTn1 = (bf16*)(ws+WTn1O); bf16* WTn2 = (bf16*)(ws+WTn2O);
  float* eS = (float*)(ws+eSO); float* nS = (float*)(ws+nSO);
  bf16* xn0 = (bf16*)(ws+xn0O);
  bf16* lnnW = (bf16*)(ws+lnnWO); bf16* lnnB = (bf16*)(ws+lnnBO);
  bf16* bc = (bf16*)(ws+bcO); int* flag = (int*)(ws+flagO);
  float2* eMR = (float2*)(ws+eMRO);

  hipMemsetAsync(ws+eSO, 0, (size_t)2*BB*2*4, stream);
  hipMemsetAsync(ws+nSO, 0, (size_t)3*BB*2*4, stream);

  k_prep<<<379, 256, 0, stream>>>(nodes, eW0f, eW0r, eW1, eW2, nW0, nW1, nW2,
                                  ln_ew, ln_eb, ln_nw, ln_nb,
                                  eb0f, eb0r, eb1, eb2, nb0, nb1, nb2,
                                  WTpd, WTps, WTe0e, WTe1, WTe2, WTn0, WTn1, WTn2,
                                  lnwP, lnbP, xn0, lnnW, lnnB, bc, flag);
  k_p0<<<BB, 256, 40960, stream>>>(xn0, WTpd, WTps, bc, Xd, Xs);

  dim3 eg(64, 8, CC);   // (j, b-group of 16, c); 4 waves x 4 b each
  dim3 ng(BB, CC);

  k_edge<0><<<eg, 256, 49152, stream>>>(edges, Xd, Xs, agg, eS, eMR, WTe0e, WTe1, WTe2, lnwP, lnbP, bc);
  k_nodeA<0><<<ng, 256, 57344, stream>>>(xn0, xc, agg, xt, nS, WTn0, WTn1, WTn2, bc);
  k_nodeB<0><<<BB, 256, 49152, stream>>>(xt, nS, lnnW, lnnB, xc, Xd, Xs, WTpd, WTps, bc, eS, eMR);

  k_edge<1><<<eg, 256, 73728, stream>>>(edges, Xd, Xs, agg, eS, eMR, WTe0e, WTe1, WTe2, lnwP, lnbP, bc);
  k_nodeA<1><<<ng, 256, 57344, stream>>>(xn0, xc, agg, xt, nS, WTn0, WTn1, WTn2, bc);
  k_nodeB<1><<<BB, 256, 49152, stream>>>(xt, nS, lnnW, lnnB, xc, Xd, Xs, WTpd, WTps, bc, eS, eMR);

  k_edge<2><<<eg, 256, 73728, stream>>>(edges, Xd, Xs, agg, eS, eMR, WTe0e, WTe1, WTe2, lnwP, lnbP, bc);
  k_nodeA<2><<<ng, 256, 57344, stream>>>(xn0, xc, agg, xt, nS, WTn0, WTn1, WTn2, bc);
  k_final<<<BB, 256, 0, stream>>>(xt, nS, lnnW, lnnB, flag, d_out);
}

// Round 14
// 280.040 us; speedup vs baseline: 1.3168x; 1.0351x over previous
//
#include <hip/hip_runtime.h>

typedef __bf16 bf16;
typedef __attribute__((ext_vector_type(8))) __bf16 bf16x8;
typedef __attribute__((ext_vector_type(4))) __bf16 bf16x4;
typedef __attribute__((ext_vector_type(4))) float f32x4;

#define MFMA16(a,b,c) __builtin_amdgcn_mfma_f32_16x16x32_bf16((a),(b),(c),0,0,0)

#define CC 2
#define BB 128
#define EPAD 4096           // 64 dst * 64 padded src-rows
#define EDGE_CNT_INV (1.0f/516096.0f)   // C*4032*64
#define NODE_CNT_INV (1.0f/8192.0f)     // C*64*64
#define LNEPS 1e-5f

// bias pack offsets (elements) in bc[]
#define BC_EB0F 0
#define BC_EB0R 128
#define BC_EB1  384
#define BC_EB2  768
#define BC_NB0  1152
#define BC_NB1  1536
#define BC_NB2  1920
#define BC_TOT  2304

static __device__ __forceinline__ f32x4 zf4(){ f32x4 z = {0.f,0.f,0.f,0.f}; return z; }

// async global->LDS DMA, 16B per lane; LDS dest = base + lane*16 (HW), src per-lane
static __device__ __forceinline__ void dma16(char* lds, const char* g){
  __builtin_amdgcn_global_load_lds(
    (const __attribute__((address_space(1))) unsigned int*)g,
    (__attribute__((address_space(3))) unsigned int*)lds,
    16, 0, 0);
}

// ---- dtype hedge (used ONLY in k_prep) ----
static __device__ __forceinline__ bool detectBf16(const void* p){
  const unsigned short* u = (const unsigned short*)p;
  int ok = 0;
#pragma unroll
  for (int i = 0; i < 64; ++i){
    unsigned v = u[i];
    unsigned e = (v >> 7) & 0xFFu;
    ok += (int)(((e >= 100u) && (e <= 150u)) || (v == 0u));
  }
  return ok >= 58;
}

static __device__ __forceinline__ float ldS(const void* p, long i, bool b16){
  return b16 ? (float)(((const bf16*)p)[i]) : ((const float*)p)[i];
}
static __device__ __forceinline__ void ld8(const void* p, long i, bool b16, float* o){
  if (b16){
    bf16x8 v = *(const bf16x8*)((const bf16*)p + i);
#pragma unroll
    for (int u=0;u<8;u++) o[u] = (float)v[u];
  } else {
    const float* f = (const float*)p + i;
    float4 a = *(const float4*)f; float4 b = *(const float4*)(f+4);
    o[0]=a.x;o[1]=a.y;o[2]=a.z;o[3]=a.w;o[4]=b.x;o[5]=b.y;o[6]=b.z;o[7]=b.w;
  }
}

// ---- LDS swizzles ----
static __device__ __forceinline__ unsigned sw128(unsigned row, unsigned cb){
  return row*128u + (cb ^ ((row&7u)<<4));
}
static __device__ __forceinline__ unsigned sw256(unsigned row, unsigned cb){
  return row*256u + (cb ^ ((row&7u)<<4));
}

static __device__ __forceinline__ void stage64(char* lds, const bf16* src, int tid){
#pragma unroll
  for (int q=0;q<2;q++){
    int idx = tid + q*256;
    int r = idx>>3; unsigned cb = (unsigned)((idx&7)*16);
    *(int4*)(lds + sw128((unsigned)r, cb)) = *(const int4*)((const char*)src + r*128 + cb);
  }
}
static __device__ __forceinline__ void stage128(char* lds, const bf16* src, int tid){
#pragma unroll
  for (int q=0;q<4;q++){
    int idx = tid + q*256;
    int r = idx>>4; unsigned cb = (unsigned)((idx&15)*16);
    *(int4*)(lds + sw256((unsigned)r, cb)) = *(const int4*)((const char*)src + r*256 + cb);
  }
}
// linear 8KB stage (no swizzle)
static __device__ __forceinline__ void stageLin(char* lds, const char* src, int tid){
#pragma unroll
  for (int q=0;q<2;q++){
    int idx = tid + q*256;
    *(int4*)(lds + idx*16) = *(const int4*)(src + idx*16);
  }
}

static __device__ __forceinline__ bf16x8 frd64(const char* p, int row, int ks, int lane){
  return *(const bf16x8*)(p + sw128((unsigned)row, (unsigned)(ks*64 + ((lane>>4)<<4))));
}
static __device__ __forceinline__ bf16x8 frd256(const char* p, int row, int ks, int lane){
  return *(const bf16x8*)(p + sw256((unsigned)row, (unsigned)(ks*64 + ((lane>>4)<<4))));
}

// GEMM with A from LDS
template<int NMT>
static __device__ __forceinline__ void gemm64(const char* wlds, const char* hlds, int lane, f32x4 (*acc)[NMT]){
  int m15 = lane & 15;
  bf16x8 af[4][2];
#pragma unroll
  for (int nt=0;nt<4;nt++){
    af[nt][0] = frd64(wlds, nt*16+m15, 0, lane);
    af[nt][1] = frd64(wlds, nt*16+m15, 1, lane);
  }
#pragma unroll
  for (int mt=0;mt<NMT;mt++){
    bf16x8 b0 = frd64(hlds, mt*16+m15, 0, lane);
    bf16x8 b1 = frd64(hlds, mt*16+m15, 1, lane);
#pragma unroll
    for (int nt=0;nt<4;nt++){
      acc[nt][mt] = MFMA16(af[nt][0], b0, acc[nt][mt]);
      acc[nt][mt] = MFMA16(af[nt][1], b1, acc[nt][mt]);
    }
  }
}

template<int NMT>
static __device__ __forceinline__ void accZero(f32x4 (*acc)[NMT]){
#pragma unroll
  for (int a=0;a<4;a++){ for (int m=0;m<NMT;m++) acc[a][m] = zf4(); }
}
template<int NMT>
static __device__ __forceinline__ void accBias(const bf16* bias, int lane, f32x4 (*acc)[NMT]){
  int hi = lane>>4;
#pragma unroll
  for (int nt=0;nt<4;nt++){
    f32x4 bv;
#pragma unroll
    for (int r=0;r<4;r++) bv[r] = (float)bias[nt*16 + hi*4 + r];
#pragma unroll
    for (int mt=0;mt<NMT;mt++) acc[nt][mt] = bv;
  }
}
template<int NMT>
static __device__ __forceinline__ void epiRelu(char* hlds, int lane, f32x4 (*acc)[NMT]){
  int hi = lane>>4, m15 = lane&15;
#pragma unroll
  for (int nt=0;nt<4;nt++){
#pragma unroll
    for (int mt=0;mt<NMT;mt++){
      f32x4 v = acc[nt][mt];
      bf16x4 o;
#pragma unroll
      for (int r=0;r<4;r++){
        float t = v[r];
        t = t > 0.f ? t : 0.f;
        o[r] = (bf16)t;
      }
      *(bf16x4*)(hlds + sw128((unsigned)(mt*16+m15), (unsigned)(nt*32 + hi*8))) = o;
    }
  }
}

// =================== PREP ===================
__global__ void k_prep(const void* nodes,
    const void* eW0f, const void* eW0r, const void* eW1, const void* eW2,
    const void* nW0, const void* nW1, const void* nW2,
    const void* ln_ew, const void* ln_eb, const void* ln_nw, const void* ln_nb,
    const void* eb0f, const void* eb0r, const void* eb1, const void* eb2,
    const void* nb0, const void* nb1, const void* nb2,
    bf16* WTpd, bf16* WTps, bf16* WTe0e, bf16* WTe1, bf16* WTe2,
    bf16* WTn0, bf16* WTn1, bf16* WTn2,
    bf16* lnwP, bf16* lnbP,
    bf16* xn0, bf16* lnnW, bf16* lnnB, bf16* bc, int* flag)
{
  bool b16 = detectBf16(nodes);
  int tid = threadIdx.x, blk = blockIdx.x;
  if (blk < 256){
    int t = blk>>7, c = (blk>>6)&1, j = blk&63;
    int k = tid>>2, part = tid&3;
    long dofs = (((long)(t*CC + c))*EPAD + j*64 + k)*64 + part*16;
    if (k < 63){
      int i = k + (k>=j ? 1 : 0);
      int eref = i*63 + j - (j>i ? 1 : 0);
      long sofs = (((long)(t*CC + c))*4032 + eref)*64 + part*16;
      float o[8]; bf16x8 v;
      ld8(ln_ew, sofs,   b16, o); for (int u=0;u<8;u++) v[u]=(bf16)o[u]; *(bf16x8*)(lnwP+dofs)   = v;
      ld8(ln_ew, sofs+8, b16, o); for (int u=0;u<8;u++) v[u]=(bf16)o[u]; *(bf16x8*)(lnwP+dofs+8) = v;
      ld8(ln_eb, sofs,   b16, o); for (int u=0;u<8;u++) v[u]=(bf16)o[u]; *(bf16x8*)(lnbP+dofs)   = v;
      ld8(ln_eb, sofs+8, b16, o); for (int u=0;u<8;u++) v[u]=(bf16)o[u]; *(bf16x8*)(lnbP+dofs+8) = v;
    } else {
      bf16x8 z; for (int u=0;u<8;u++) z[u]=(bf16)0.f;
      *(bf16x8*)(lnwP+dofs)=z; *(bf16x8*)(lnwP+dofs+8)=z;
      *(bf16x8*)(lnbP+dofs)=z; *(bf16x8*)(lnbP+dofs+8)=z;
    }
    return;
  }
  int job = blk - 256;
  if (job < 46){
    const void* src = nullptr; bf16* dst = nullptr; int K = 64; long so = 0;
    if (job < 6){        int t=job>>1, c=job&1; dst = WTpd + (long)(t*CC+c)*4096;
      if (t==0){ src=eW0f; so=(long)c*128*64; } else { src=eW0r; so=((long)(t-1)*CC+c)*192*64; } }
    else if (job < 12){  int q=job-6; int t=q>>1,c=q&1; dst = WTps + (long)(t*CC+c)*4096;
      if (t==0){ src=eW0f; so=(long)c*128*64 + 64*64; } else { src=eW0r; so=((long)(t-1)*CC+c)*192*64 + 64*64; } }
    else if (job < 16){  int q=job-12; int t=q>>1,c=q&1; dst=WTe0e + (long)(t*CC+c)*4096; src=eW0r; so=((long)t*CC+c)*192*64 + 128*64; }
    else if (job < 22){  int q=job-16; int t=q>>1,c=q&1; dst=WTe1 + (long)(t*CC+c)*4096; src=eW1; so=((long)t*CC+c)*4096; }
    else if (job < 28){  int q=job-22; int t=q>>1,c=q&1; dst=WTe2 + (long)(t*CC+c)*4096; src=eW2; so=((long)t*CC+c)*4096; }
    else if (job < 34){  int q=job-28; int t=q>>1,c=q&1; dst=WTn0 + (long)(t*CC+c)*8192; src=nW0; so=((long)t*CC+c)*128*64; K=128; }
    else if (job < 40){  int q=job-34; int t=q>>1,c=q&1; dst=WTn1 + (long)(t*CC+c)*4096; src=nW1; so=((long)t*CC+c)*4096; }
    else              {  int q=job-40; int t=q>>1,c=q&1; dst=WTn2 + (long)(t*CC+c)*4096; src=nW2; so=((long)t*CC+c)*4096; }
    for (int idx = tid; idx < K*64; idx += 256){
      int n = idx & 63, k = idx >> 6;
      dst[(long)n*K + k] = (bf16)ldS(src, so + (long)k*64 + n, b16);
    }
  } else if (job < 110){
    long base = (long)(job-46)*8192;
#pragma unroll
    for (int k=0;k<4;k++){
      long o = base + k*2048 + tid*8;
      float t[8]; ld8(nodes, o, b16, t);
      bf16x8 v;
#pragma unroll
      for (int u=0;u<8;u++) v[u]=(bf16)t[u];
      *(bf16x8*)(xn0 + o) = v;
    }
  } else if (job < 122){
    int q = job-110;
    const void* src = (q<6) ? ln_nw : ln_nb;
    bf16* dst = (q<6) ? lnnW : lnnB;
    long base = (long)(q%6)*4096;
#pragma unroll
    for (int k=0;k<2;k++){
      long o = base + k*2048 + tid*8;
      float t[8]; ld8(src, o, b16, t);
      bf16x8 v;
#pragma unroll
      for (int u=0;u<8;u++) v[u]=(bf16)t[u];
      *(bf16x8*)(dst + o) = v;
    }
  } else {
    for (int idx = tid; idx < BC_TOT; idx += 256){
      float v;
      if      (idx < BC_EB0R) v = ldS(eb0f, idx - BC_EB0F, b16);
      else if (idx < BC_EB1 ) v = ldS(eb0r, idx - BC_EB0R, b16);
      else if (idx < BC_EB2 ) v = ldS(eb1,  idx - BC_EB1,  b16);
      else if (idx < BC_NB0 ) v = ldS(eb2,  idx - BC_EB2,  b16);
      else if (idx < BC_NB1 ) v = ldS(nb0,  idx - BC_NB0,  b16);
      else if (idx < BC_NB2 ) v = ldS(nb1,  idx - BC_NB1,  b16);
      else                    v = ldS(nb2,  idx - BC_NB2,  b16);
      bc[idx] = (bf16)v;
    }
    if (tid == 0) flag[0] = b16 ? 1 : 0;
  }
}

// =================== P0: Xd/Xs (bf16) = nodes@W0d + b0 / nodes@W0s ===================
__global__ __launch_bounds__(256,2) void k_p0(const bf16* xn0,
    const bf16* WTpd, const bf16* WTps, const bf16* bc, bf16* Xd, bf16* Xs)
{
  int tid=threadIdx.x, lane=tid&63, w=tid>>6;
  int b = blockIdx.x;
  extern __shared__ char sm[];
  char* xn = sm;
  char* Wp = sm + 8192;
  stage64(xn, xn0 + (long)b*4096, tid);
  stage64(Wp,         WTpd + 0,    tid);
  stage64(Wp + 8192,  WTps + 0,    tid);
  stage64(Wp + 16384, WTpd + 4096, tid);
  stage64(Wp + 24576, WTps + 4096, tid);
  __syncthreads();
  int c = w>>1, p = w&1;
  f32x4 acc[4][4];
  if (p==0) accBias<4>(bc + BC_EB0F + c*64, lane, acc);
  else accZero<4>(acc);
  gemm64<4>(Wp + (c*2+p)*8192, xn, lane, acc);
  int hi=lane>>4, m15=lane&15;
  bf16* dst = (p==0 ? Xd : Xs) + ((long)c*BB + b)*64*64;
#pragma unroll
  for (int nt=0;nt<4;nt++){
#pragma unroll
    for (int mt=0;mt<4;mt++){
      f32x4 v = acc[nt][mt];
      bf16x4 o = {(bf16)v[0],(bf16)v[1],(bf16)v[2],(bf16)v[3]};
      *(bf16x4*)(dst + (long)(mt*16+m15)*64 + nt*16+hi*4) = o;
    }
  }
}

// =================== EDGE kernel ===================
// Grid (j=64, bg=4, c=2) = 512 blocks = ONE residency round at 2 blocks/CU.
// Each wave loops 8 b. Weights + lnw/lnb (j,c-invariant) staged to LDS once per
// block (amortized over 8 chains). Edge tile DMA'd global->LDS (zero VGPR) and
// normalized in place. eMR for all 8 b hoisted to kernel start.
template<int T>
__global__ __launch_bounds__(256,2) void k_edge(
    bf16* edges, const bf16* Xd, const bf16* Xs, float* agg, float* eS,
    const float2* eMR,
    const bf16* WTe0e, const bf16* WTe1, const bf16* WTe2,
    const bf16* lnwP, const bf16* lnbP, const bf16* bc)
{
  int tid=threadIdx.x, lane=tid&63, w=tid>>6;
  int j = blockIdx.x, bg = blockIdx.y, c = blockIdx.z;
  extern __shared__ char sm[];
  char* Wl1 = sm;
  char* Wl2 = sm + 8192;
  char* Wl0 = sm + 16384;            // T>0 only
  char* lwL = sm + 24576;            // T>0 only, linear [64][64]
  char* lbL = sm + 32768;
  char* hb  = sm + (T>0 ? 40960 : 16384) + w*8192;   // per-wave [64][64] bf16

  int hi = lane>>4, m15 = lane&15;
  int mrow = lane>>3;
  unsigned cbyte = (unsigned)((lane&7)*16);
  int cbk = (lane&7)*8;
  int b0 = bg*32 + w*8;

  // hoisted per-b LN stats for all 8 chains
  float2 mr8[8];
  if (T>0){
#pragma unroll
    for (int t=0;t<8;t++) mr8[t] = eMR[(T-1)*BB + b0 + t];
  }

  stage64(Wl1, WTe1 + (long)(T*CC+c)*4096, tid);
  stage64(Wl2, WTe2 + (long)(T*CC+c)*4096, tid);
  if (T>0){
    stage64(Wl0, WTe0e + (long)((T-1)*CC+c)*4096, tid);
    const char* lwg = (const char*)(lnwP + (((long)(T-1)*CC+c)*EPAD + (long)j*64)*64);
    const char* lbg = (const char*)(lnbP + (((long)(T-1)*CC+c)*EPAD + (long)j*64)*64);
    stageLin(lwL, lwg, tid);
    stageLin(lbL, lbg, tid);
  }
  __syncthreads();

  for (int t=0; t<8; t++){
    int b = b0 + t;
    long cb = (long)c*BB + b;
    bf16* erow = edges + (cb*EPAD + (long)j*64)*64;
    const bf16* xdrow = Xd + (cb*64 + j)*64;
    const bf16* xsbase = Xs + cb*4096;

    f32x4 acc[4][4];

    if (T==0){
      bf16x8 xd8v = *(const bf16x8*)(xdrow + cbk);
      float xd8[8];
#pragma unroll
      for (int u=0;u<8;u++) xd8[u] = (float)xd8v[u];
#pragma unroll
      for (int it=0; it<8; it++){
        int m = mrow + it*8;
        int i = m + (m>=j ? 1 : 0); if (i>63) i = 63;
        bf16x8 y8 = *(const bf16x8*)(xsbase + (long)i*64 + cbk);
        bf16x8 o;
#pragma unroll
        for (int u=0;u<8;u++){
          float tt = xd8[u] + (float)y8[u];
          tt = tt > 0.f ? tt : 0.f;
          o[u] = (bf16)tt;
        }
        *(bf16x8*)(hb + sw128((unsigned)m, (unsigned)(cbk*2))) = o;
      }
      accBias<4>(bc + BC_EB1 + (T*CC+c)*64, lane, acc);
      gemm64<4>(Wl1, hb, lane, acc);
      epiRelu<4>(hb, lane, acc);
      accBias<4>(bc + BC_EB2 + (T*CC+c)*64, lane, acc);
      gemm64<4>(Wl2, hb, lane, acc);
    } else {
      float mu = mr8[t].x, rs = mr8[t].y;
      // drain prior chain's hb reads, then DMA e tile into hb (zero VGPRs)
      asm volatile("s_waitcnt lgkmcnt(0)" ::: "memory");
#pragma unroll
      for (int it=0; it<8; it++)
        dma16(hb + it*1024, (const char*)erow + it*1024 + (long)lane*16);
      asm volatile("s_waitcnt vmcnt(0)" ::: "memory");
      __builtin_amdgcn_sched_barrier(0);
      // normalize in place: linear read -> swizzled write (same it-chunk)
#pragma unroll
      for (int it=0; it<8; it++){
        int m = mrow + it*8;
        bf16x8 e  = *(const bf16x8*)(hb  + lane*16 + it*1024);
        bf16x8 wv = *(const bf16x8*)(lwL + lane*16 + it*1024);
        bf16x8 bv = *(const bf16x8*)(lbL + lane*16 + it*1024);
        bf16x8 o;
#pragma unroll
        for (int u=0;u<8;u++){
          float tt = ((float)e[u] - mu) * rs;
          tt = tt * (float)wv[u] + (float)bv[u];
          o[u] = (bf16)tt;
        }
        *(bf16x8*)(hb + sw128((unsigned)m, cbyte)) = o;
      }
      // epilogue0 operands (hidden under GEMM0)
      bf16x4 xdv[4], xsv[4][4];
#pragma unroll
      for (int nt=0;nt<4;nt++) xdv[nt] = *(const bf16x4*)(xdrow + nt*16 + hi*4);
#pragma unroll
      for (int mt=0;mt<4;mt++){
        int m = mt*16 + m15;
        int i = m + (m>=j ? 1 : 0); if (i>63) i=63;
#pragma unroll
        for (int nt=0;nt<4;nt++)
          xsv[mt][nt] = *(const bf16x4*)(xsbase + (long)i*64 + nt*16 + hi*4);
      }
      accZero<4>(acc);
      gemm64<4>(Wl0, hb, lane, acc);
      // epilogue0: + Xd'[j] + Xs[i(m)], relu -> h0
#pragma unroll
      for (int mt=0;mt<4;mt++){
        int m = mt*16 + m15;
#pragma unroll
        for (int nt=0;nt<4;nt++){
          f32x4 v = acc[nt][mt];
          float t0 = v[0] + (float)xdv[nt][0] + (float)xsv[mt][nt][0];
          float t1 = v[1] + (float)xdv[nt][1] + (float)xsv[mt][nt][1];
          float t2 = v[2] + (float)xdv[nt][2] + (float)xsv[mt][nt][2];
          float t3 = v[3] + (float)xdv[nt][3] + (float)xsv[mt][nt][3];
          bf16x4 o;
          o[0] = (bf16)(t0>0.f?t0:0.f); o[1] = (bf16)(t1>0.f?t1:0.f);
          o[2] = (bf16)(t2>0.f?t2:0.f); o[3] = (bf16)(t3>0.f?t3:0.f);
          *(bf16x4*)(hb + sw128((unsigned)m, (unsigned)(nt*32+hi*8))) = o;
        }
      }
      accBias<4>(bc + BC_EB1 + (T*CC+c)*64, lane, acc);
      gemm64<4>(Wl1, hb, lane, acc);
      epiRelu<4>(hb, lane, acc);
      accBias<4>(bc + BC_EB2 + (T*CC+c)*64, lane, acc);
      gemm64<4>(Wl2, hb, lane, acc);
    }

    // ---- per-chain epilogue ----
    if (m15 == 15){
#pragma unroll
      for (int nt=0;nt<4;nt++) acc[nt][3] = zf4();
    }
    if (T < 2){
      float s1=0.f, s2=0.f;
#pragma unroll
      for (int nt=0;nt<4;nt++){ for (int mt=0;mt<4;mt++){ for (int r=0;r<4;r++){
        float v = acc[nt][mt][r]; s1 += v; s2 = fmaf(v,v,s2);
      }}}
#pragma unroll
      for (int d=1; d<64; d<<=1){ s1 += __shfl_xor(s1,d); s2 += __shfl_xor(s2,d); }
      if (lane == 0){
        atomicAdd(&eS[((long)T*BB + b)*2],     s1);
        atomicAdd(&eS[((long)T*BB + b)*2 + 1], s2);
      }
      // store edges via LDS transpose -> coalesced global
#pragma unroll
      for (int mt=0;mt<4;mt++){
        int m = mt*16 + m15;
#pragma unroll
        for (int nt=0;nt<4;nt++){
          f32x4 v = acc[nt][mt];
          bf16x4 o = {(bf16)v[0],(bf16)v[1],(bf16)v[2],(bf16)v[3]};
          *(bf16x4*)(hb + sw128((unsigned)m, (unsigned)(nt*32+hi*8))) = o;
        }
      }
#pragma unroll
      for (int it=0; it<8; it++){
        int m = mrow + it*8;
        *(int4*)((char*)erow + m*128 + cbyte) = *(const int4*)(hb + sw128((unsigned)m, cbyte));
      }
    }
    // aggregation: agg[c,b,j,n] = sum_m out[n,m]
#pragma unroll
    for (int nt=0;nt<4;nt++){
      float p0 = acc[nt][0][0]+acc[nt][1][0]+acc[nt][2][0]+acc[nt][3][0];
      float p1 = acc[nt][0][1]+acc[nt][1][1]+acc[nt][2][1]+acc[nt][3][1];
      float p2 = acc[nt][0][2]+acc[nt][1][2]+acc[nt][2][2]+acc[nt][3][2];
      float p3 = acc[nt][0][3]+acc[nt][1][3]+acc[nt][2][3]+acc[nt][3][3];
      unsigned base = (unsigned)(nt*64 + hi*16);
      float2 q0 = {p0,p1}, q1 = {p2,p3};
      *(float2*)(hb + (unsigned)m15*256u + (base       ^ (((unsigned)(m15&7))<<4))) = q0;
      *(float2*)(hb + (unsigned)m15*256u + ((base+8u)  ^ (((unsigned)(m15&7))<<4))) = q1;
    }
    float s = 0.f;
#pragma unroll
    for (int r=0;r<16;r++){
      s += *(const float*)(hb + (unsigned)r*256u + ((((unsigned)lane)*4u) ^ (((unsigned)(r&7))<<4)));
    }
    agg[(cb*64 + j)*64 + lane] = s;
  }
}

// =================== NODE A ===================
template<int T>
__global__ __launch_bounds__(256,2) void k_nodeA(const bf16* xn0,
    const bf16* xcur, const float* agg, float* xtilde, float* nS,
    const bf16* WTn0, const bf16* WTn1, const bf16* WTn2, const bf16* bc)
{
  int tid=threadIdx.x, lane=tid&63, w=tid>>6;
  int b = blockIdx.x, c = blockIdx.y;
  extern __shared__ char sm[];
  char* nin = sm;
  char* W0l = sm + 16384;
  char* W1l = sm + 32768;
  char* W2l = sm + 40960;
  char* hb  = sm + 49152 + w*2048;
  long cb = (long)c*BB + b;

#pragma unroll
  for (int q=0;q<2;q++){
    int idx = tid + q*256;
    int r = idx>>3; int e8 = (idx&7)*8;
    bf16x8 o;
    if (T==0) o = *(const bf16x8*)(xn0 + ((long)b*64 + r)*64 + e8);
    else      o = *(const bf16x8*)(xcur + (cb*64 + r)*64 + e8);
    *(bf16x8*)(nin + sw256((unsigned)r, (unsigned)(e8*2))) = o;
  }
#pragma unroll
  for (int q=0;q<2;q++){
    int idx = tid + q*256;
    int r = idx>>3; int e8 = (idx&7)*8;
    const float* ap = agg + (cb*64 + r)*64 + e8;
    float4 x = *(const float4*)ap; float4 y = *(const float4*)(ap+4);
    bf16x8 o = {(bf16)x.x,(bf16)x.y,(bf16)x.z,(bf16)x.w,(bf16)y.x,(bf16)y.y,(bf16)y.z,(bf16)y.w};
    *(bf16x8*)(nin + sw256((unsigned)r, (unsigned)(128 + e8*2))) = o;
  }
  stage128(W0l, WTn0 + (long)(T*CC+c)*8192, tid);
  stage64 (W1l, WTn1 + (long)(T*CC+c)*4096, tid);
  stage64 (W2l, WTn2 + (long)(T*CC+c)*4096, tid);
  __syncthreads();

  int hi=lane>>4, m15=lane&15;
  int m0 = w*16;
  long bofs = (long)(T*CC+c)*64;
  f32x4 a1[4][1];
  accBias<1>(bc + BC_NB0 + bofs, lane, a1);
  {
    bf16x8 bv[4];
#pragma unroll
    for (int ks=0;ks<4;ks++) bv[ks] = frd256(nin, m0+m15, ks, lane);
#pragma unroll
    for (int nt=0;nt<4;nt++){
#pragma unroll
      for (int ks=0;ks<4;ks++){
        bf16x8 av = frd256(W0l, nt*16+m15, ks, lane);
        a1[nt][0] = MFMA16(av, bv[ks], a1[nt][0]);
      }
    }
  }
  epiRelu<1>(hb, lane, a1);
  f32x4 a2[4][1];
  accBias<1>(bc + BC_NB1 + bofs, lane, a2);
  gemm64<1>(W1l, hb, lane, a2);
  epiRelu<1>(hb, lane, a2);
  f32x4 a3[4][1];
  accBias<1>(bc + BC_NB2 + bofs, lane, a3);
  gemm64<1>(W2l, hb, lane, a3);
  float s1=0.f, s2=0.f;
#pragma unroll
  for (int nt=0;nt<4;nt++){
#pragma unroll
    for (int r=0;r<4;r++){
      float v = a3[nt][0][r];
      s1 += v; s2 = fmaf(v,v,s2);
    }
  }
#pragma unroll
  for (int d=1; d<64; d<<=1){ s1 += __shfl_xor(s1,d); s2 += __shfl_xor(s2,d); }
  if (lane == 0){
    atomicAdd(&nS[((long)T*BB + b)*2],     s1);
    atomicAdd(&nS[((long)T*BB + b)*2 + 1], s2);
  }
#pragma unroll
  for (int nt=0;nt<4;nt++)
    *(f32x4*)(xtilde + (cb*64 + m0 + m15)*64 + nt*16 + hi*4) = a3[nt][0];
}

// =================== NODE B ===================
template<int T>
__global__ __launch_bounds__(256,2) void k_nodeB(
    const float* xtilde, const float* nS, const bf16* lnnW, const bf16* lnnB,
    bf16* xcur, bf16* Xd, bf16* Xs,
    const bf16* WTpd, const bf16* WTps, const bf16* bc,
    const float* eS, float2* eMR)
{
  int tid=threadIdx.x, lane=tid&63, w=tid>>6;
  int b = blockIdx.x;
  extern __shared__ char sm[];
  char* xl = sm;
  char* Wp = sm + 16384;
  // finalize edge-LN stats for this b (consumed by edge<T+1>)
  if (tid == 0 && T < 2){
    float2 st = *(const float2*)(eS + ((long)T*BB + b)*2);
    float mu = st.x * EDGE_CNT_INV;
    float rs = rsqrtf(st.y * EDGE_CNT_INV - mu*mu + LNEPS);
    eMR[(long)T*BB + b] = make_float2(mu, rs);
  }
  float2 st = *(const float2*)(nS + ((long)T*BB + b)*2);
  float mu = st.x * NODE_CNT_INV;
  float rs = rsqrtf(st.y * NODE_CNT_INV - mu*mu + LNEPS);
  {
    int r = tid>>1, k0 = (tid&1)*32;
    int cc = r>>6, node = r&63;
    const float* xt = xtilde + (((long)cc*BB + b)*64 + node)*64 + k0;
    long lnofs = (((long)T*CC + cc)*64 + node)*64 + k0;
    bf16* xc = xcur + (((long)cc*BB + b)*64 + node)*64 + k0;
#pragma unroll
    for (int u=0;u<32;u+=8){
      float4 xa = *(const float4*)(xt+u); float4 xb = *(const float4*)(xt+u+4);
      bf16x8 wv8 = *(const bf16x8*)(lnnW + lnofs + u);
      bf16x8 bv8 = *(const bf16x8*)(lnnB + lnofs + u);
      float x8[8] = {xa.x,xa.y,xa.z,xa.w,xb.x,xb.y,xb.z,xb.w};
      bf16x8 o;
#pragma unroll
      for (int q=0;q<8;q++) o[q] = (bf16)((x8[q]-mu)*rs*(float)wv8[q] + (float)bv8[q]);
      *(bf16x8*)(xc + u) = o;
      *(bf16x8*)(xl + sw128((unsigned)r, (unsigned)((k0+u)*2))) = o;
    }
  }
  stage64(Wp,         WTpd + (long)((T+1)*CC+0)*4096, tid);
  stage64(Wp + 8192,  WTps + (long)((T+1)*CC+0)*4096, tid);
  stage64(Wp + 16384, WTpd + (long)((T+1)*CC+1)*4096, tid);
  stage64(Wp + 24576, WTps + (long)((T+1)*CC+1)*4096, tid);
  __syncthreads();
  int c = w>>1, p = w&1;
  f32x4 acc[4][4];
  if (p==0) accBias<4>(bc + BC_EB0R + (T*CC+c)*64, lane, acc);
  else accZero<4>(acc);
  gemm64<4>(Wp + (c*2+p)*8192, xl + c*64*128, lane, acc);
  int hi=lane>>4, m15=lane&15;
  bf16* dst = (p==0 ? Xd : Xs) + ((long)c*BB + b)*64*64;
#pragma unroll
  for (int nt=0;nt<4;nt++){
#pragma unroll
    for (int mt=0;mt<4;mt++){
      f32x4 v = acc[nt][mt];
      bf16x4 o = {(bf16)v[0],(bf16)v[1],(bf16)v[2],(bf16)v[3]};
      *(bf16x4*)(dst + (long)(mt*16+m15)*64 + nt*16+hi*4) = o;
    }
  }
}

// =================== FINAL ===================
__global__ __launch_bounds__(256,2) void k_final(
    const float* xtilde, const float* nS, const bf16* lnnW, const bf16* lnnB,
    const int* flag, void* dout)
{
  bool b16 = flag[0] != 0;
  int tid = threadIdx.x; int b = blockIdx.x;
  float2 st = *(const float2*)(nS + ((long)2*BB + b)*2);
  float mu = st.x * NODE_CNT_INV;
  float rs = rsqrtf(st.y * NODE_CNT_INV - mu*mu + LNEPS);
  int r = tid>>2, k0 = (tid&3)*16;
  float o16[16];
#pragma unroll
  for (int u=0;u<16;u++) o16[u] = 0.f;
#pragma unroll
  for (int c=0;c<2;c++){
    const float* xt = xtilde + (((long)c*BB + b)*64 + r)*64 + k0;
    long lnofs = (((long)2*CC + c)*64 + r)*64 + k0;
#pragma unroll
    for (int u=0;u<16;u+=8){
      float4 xa = *(const float4*)(xt+u); float4 xb = *(const float4*)(xt+u+4);
      bf16x8 wv8 = *(const bf16x8*)(lnnW + lnofs + u);
      bf16x8 bv8 = *(const bf16x8*)(lnnB + lnofs + u);
      float x8[8] = {xa.x,xa.y,xa.z,xa.w,xb.x,xb.y,xb.z,xb.w};
#pragma unroll
      for (int q=0;q<8;q++) o16[u+q] += (x8[q]-mu)*rs*(float)wv8[q] + (float)bv8[q];
    }
  }
  long oofs = ((long)b*64 + r)*64 + k0;
  if (b16){
    bf16x8 v0, v1;
#pragma unroll
    for (int q=0;q<8;q++){ v0[q]=(bf16)o16[q]; v1[q]=(bf16)o16[8+q]; }
    *(bf16x8*)((bf16*)dout + oofs) = v0;
    *(bf16x8*)((bf16*)dout + oofs + 8) = v1;
  } else {
    float* f = (float*)dout + oofs;
#pragma unroll
    for (int q=0;q<4;q++){
      float4 v = {o16[q*4+0], o16[q*4+1], o16[q*4+2], o16[q*4+3]};
      *(float4*)(f + q*4) = v;
    }
  }
}

// =================== host ===================
extern "C" void kernel_launch(void* const* d_in, const int* in_sizes, int n_in,
                              void* d_out, int out_size, void* d_ws, size_t ws_size,
                              hipStream_t stream)
{
  (void)in_sizes; (void)n_in; (void)out_size;
  const void* nodes = d_in[0];
  const void* eW0f = d_in[3];  const void* eb0f = d_in[4];
  const void* eW0r = d_in[5];  const void* eb0r = d_in[6];
  const void* eW1  = d_in[7];  const void* eb1  = d_in[8];
  const void* eW2  = d_in[9];  const void* eb2  = d_in[10];
  const void* nW0  = d_in[11]; const void* nb0  = d_in[12];
  const void* nW1  = d_in[13]; const void* nb1  = d_in[14];
  const void* nW2  = d_in[15]; const void* nb2  = d_in[16];
  const void* ln_nw = d_in[17]; const void* ln_nb = d_in[18];
  const void* ln_ew = d_in[19]; const void* ln_eb = d_in[20];

  char* ws = (char*)d_ws;
  size_t off = 0;
  auto A = [&](size_t n){ size_t o = off; off += (n + 255) & ~(size_t)255; return o; };
  size_t edgesO = A((size_t)CC*BB*EPAD*64*2);
  size_t XdO  = A((size_t)CC*BB*64*64*2);
  size_t XsO  = A((size_t)CC*BB*64*64*2);
  size_t xtO  = A((size_t)CC*BB*64*64*4);
  size_t aggO = A((size_t)CC*BB*64*64*4);
  size_t xcO  = A((size_t)CC*BB*64*64*2);
  size_t lnwO = A((size_t)2*CC*EPAD*64*2);
  size_t lnbO = A((size_t)2*CC*EPAD*64*2);
  size_t WTpdO = A((size_t)3*CC*4096*2);
  size_t WTpsO = A((size_t)3*CC*4096*2);
  size_t WTe0eO = A((size_t)2*CC*4096*2);
  size_t WTe1O = A((size_t)3*CC*4096*2);
  size_t WTe2O = A((size_t)3*CC*4096*2);
  size_t WTn0O = A((size_t)3*CC*8192*2);
  size_t WTn1O = A((size_t)3*CC*4096*2);
  size_t WTn2O = A((size_t)3*CC*4096*2);
  size_t eSO = A((size_t)2*BB*2*4);
  size_t nSO = A((size_t)3*BB*2*4);
  size_t xn0O = A((size_t)BB*64*64*2);
  size_t lnnWO = A((size_t)3*CC*64*64*2);
  size_t lnnBO = A((size_t)3*CC*64*64*2);
  size_t bcO = A((size_t)BC_TOT*2);
  size_t flagO = A(4);
  size_t eMRO = A((size_t)2*BB*8);
  if (ws_size < off) return;

  bf16* edges = (bf16*)(ws+edgesO);
  bf16* Xd = (bf16*)(ws+XdO);  bf16* Xs = (bf16*)(ws+XsO);
  float* xt = (float*)(ws+xtO);  float* agg = (float*)(ws+aggO);
  bf16* xc = (bf16*)(ws+xcO);
  bf16* lnwP = (bf16*)(ws+lnwO); bf16* lnbP = (bf16*)(ws+lnbO);
  bf16* WTpd = (bf16*)(ws+WTpdO); bf16* WTps = (bf16*)(ws+WTpsO);
  bf16* WTe0e = (bf16*)(ws+WTe0eO); bf16* WTe1 = (bf16*)(ws+WTe1O); bf16* WTe2 = (bf16*)(ws+WTe2O);
  bf16* WTn0 = (bf16*)(ws+WTn0O); bf16* WTn1 = (bf16*)(ws+WTn1O); bf16* WTn2 = (bf16*)(ws+WTn2O);
  float* eS = (float*)(ws+eSO); float* nS = (float*)(ws+nSO);
  bf16* xn0 = (bf16*)(ws+xn0O);
  bf16* lnnW = (bf16*)(ws+lnnWO); bf16* lnnB = (bf16*)(ws+lnnBO);
  bf16* bc = (bf16*)(ws+bcO); int* flag = (int*)(ws+flagO);
  float2* eMR = (float2*)(ws+eMRO);

  hipMemsetAsync(ws+eSO, 0, (size_t)2*BB*2*4, stream);
  hipMemsetAsync(ws+nSO, 0, (size_t)3*BB*2*4, stream);

  k_prep<<<379, 256, 0, stream>>>(nodes, eW0f, eW0r, eW1, eW2, nW0, nW1, nW2,
                                  ln_ew, ln_eb, ln_nw, ln_nb,
                                  eb0f, eb0r, eb1, eb2, nb0, nb1, nb2,
                                  WTpd, WTps, WTe0e, WTe1, WTe2, WTn0, WTn1, WTn2,
                                  lnwP, lnbP, xn0, lnnW, lnnB, bc, flag);
  k_p0<<<BB, 256, 40960, stream>>>(xn0, WTpd, WTps, bc, Xd, Xs);

  dim3 eg(64, 4, CC);   // (j, b-group of 32, c); 4 waves x 8 b each = one round
  dim3 ng(BB, CC);

  k_edge<0><<<eg, 256, 49152, stream>>>(edges, Xd, Xs, agg, eS, eMR, WTe0e, WTe1, WTe2, lnwP, lnbP, bc);
  k_nodeA<0><<<ng, 256, 57344, stream>>>(xn0, xc, agg, xt, nS, WTn0, WTn1, WTn2, bc);
  k_nodeB<0><<<BB, 256, 49152, stream>>>(xt, nS, lnnW, lnnB, xc, Xd, Xs, WTpd, WTps, bc, eS, eMR);

  k_edge<1><<<eg, 256, 73728, stream>>>(edges, Xd, Xs, agg, eS, eMR, WTe0e, WTe1, WTe2, lnwP, lnbP, bc);
  k_nodeA<1><<<ng, 256, 57344, stream>>>(xn0, xc, agg, xt, nS, WTn0, WTn1, WTn2, bc);
  k_nodeB<1><<<BB, 256, 49152, stream>>>(xt, nS, lnnW, lnnB, xc, Xd, Xs, WTpd, WTps, bc, eS, eMR);

  k_edge<2><<<eg, 256, 73728, stream>>>(edges, Xd, Xs, agg, eS, eMR, WTe0e, WTe1, WTe2, lnwP, lnbP, bc);
  k_nodeA<2><<<ng, 256, 57344, stream>>>(xn0, xc, agg, xt, nS, WTn0, WTn1, WTn2, bc);
  k_final<<<BB, 256, 0, stream>>>(xt, nS, lnnW, lnnB, flag, d_out);
}